// Round 1
// baseline (204.856 us; speedup 1.0000x reference)
//
#include <hip/hip_runtime.h>

// B=4, N=1024, E=1024, H=16, D=64.  All matmuls in bf16 MFMA (16x16x32), fp32 accum.
// Raw-reshape trick: per batch, head h's Q/K/V is the contiguous [1024,64] slab at
// flat offset h*65536 of the [n*e] buffer; attention output written back in the same
// flat layout IS the [b,n,e] input of the FC GEMM. No physical transposes needed.

typedef __bf16 bf16x8 __attribute__((ext_vector_type(8)));
typedef float f32x4 __attribute__((ext_vector_type(4)));

__device__ __forceinline__ unsigned short f2bf(float f) {
    unsigned u = __float_as_uint(f);
    u += 0x7fffu + ((u >> 16) & 1u);   // round-to-nearest-even
    return (unsigned short)(u >> 16);
}

union FragU { uint4 u; bf16x8 v; };

__device__ __forceinline__ bf16x8 ld_frag(const unsigned short* p) {
    FragU x; x.u = *(const uint4*)p; return x.v;
}

// ---------------- fp32 -> bf16 elementwise ----------------
__global__ void cvt_bf16(const float* __restrict__ in, unsigned short* __restrict__ out, int n4) {
    int i = blockIdx.x * blockDim.x + threadIdx.x;
    int stride = gridDim.x * blockDim.x;
    for (; i < n4; i += stride) {
        float4 f = ((const float4*)in)[i];
        unsigned a = (unsigned)f2bf(f.x) | ((unsigned)f2bf(f.y) << 16);
        unsigned b = (unsigned)f2bf(f.z) | ((unsigned)f2bf(f.w) << 16);
        ((uint2*)out)[i] = make_uint2(a, b);
    }
}

// ---------------- fp32 [rows][cols] -> bf16 [cols][rows] ----------------
__global__ void transpose_cvt(const float* __restrict__ W, unsigned short* __restrict__ Wt,
                              int rows, int cols) {
    __shared__ float tile[32][33];
    int c0 = blockIdx.x * 32, r0 = blockIdx.y * 32;
    for (int i = threadIdx.y; i < 32; i += 8)
        tile[i][threadIdx.x] = W[(r0 + i) * cols + c0 + threadIdx.x];
    __syncthreads();
    for (int i = threadIdx.y; i < 32; i += 8)
        Wt[(c0 + i) * (long)rows + r0 + threadIdx.x] = f2bf(tile[threadIdx.x][i]);
}

// ---------------- bf16 GEMM: C[M,N] = A[M,K] * Bt[N,K]^T + bias ----------------
// MODE 0: N=3072, split cols into q/k/v bf16 buffers.  MODE 1: N=1024, fp32 out.
template <int MODE>
__global__ __launch_bounds__(256) void gemm64(
    const unsigned short* __restrict__ A,    // [M,1024] bf16
    const unsigned short* __restrict__ Bt,   // [N,1024] bf16 (B transposed)
    const float* __restrict__ bias,          // [N]
    unsigned short* __restrict__ qb,
    unsigned short* __restrict__ kb,
    unsigned short* __restrict__ vb,
    float* __restrict__ outf)
{
    const int K = 1024;
    __shared__ unsigned short As[64][40];
    __shared__ unsigned short Bs[64][40];
    int tn0 = blockIdx.x * 64;
    int tm0 = blockIdx.y * 64;
    int t = threadIdx.x;
    int lane = t & 63;
    int w = t >> 6;
    int wm = w >> 1, wn = w & 1;
    int lrow = lane >> 4, lcol = lane & 15;
    int srow = t >> 2, sk = (t & 3) * 8;

    f32x4 acc[2][2] = {};
    const unsigned short* pA = A + (long)(tm0 + srow) * K + sk;
    const unsigned short* pB = Bt + (long)(tn0 + srow) * K + sk;

    for (int kt = 0; kt < K; kt += 32) {
        *(uint4*)&As[srow][sk] = *(const uint4*)(pA + kt);
        *(uint4*)&Bs[srow][sk] = *(const uint4*)(pB + kt);
        __syncthreads();
        bf16x8 a0 = ld_frag(&As[wm * 32 + lcol][lrow * 8]);
        bf16x8 a1 = ld_frag(&As[wm * 32 + 16 + lcol][lrow * 8]);
        bf16x8 b0 = ld_frag(&Bs[wn * 32 + lcol][lrow * 8]);
        bf16x8 b1 = ld_frag(&Bs[wn * 32 + 16 + lcol][lrow * 8]);
        acc[0][0] = __builtin_amdgcn_mfma_f32_16x16x32_bf16(a0, b0, acc[0][0], 0, 0, 0);
        acc[0][1] = __builtin_amdgcn_mfma_f32_16x16x32_bf16(a0, b1, acc[0][1], 0, 0, 0);
        acc[1][0] = __builtin_amdgcn_mfma_f32_16x16x32_bf16(a1, b0, acc[1][0], 0, 0, 0);
        acc[1][1] = __builtin_amdgcn_mfma_f32_16x16x32_bf16(a1, b1, acc[1][1], 0, 0, 0);
        __syncthreads();
    }

    #pragma unroll
    for (int mi = 0; mi < 2; ++mi)
        #pragma unroll
        for (int ni = 0; ni < 2; ++ni) {
            int gr = tm0 + wm * 32 + mi * 16 + lrow * 4;
            int gc = tn0 + wn * 32 + ni * 16 + lcol;
            float bv = bias[gc];
            #pragma unroll
            for (int r = 0; r < 4; ++r) {
                float v = acc[mi][ni][r] + bv;
                if (MODE == 0) {
                    int sec = gc >> 10, ei = gc & 1023;
                    unsigned short* dst = sec == 0 ? qb : (sec == 1 ? kb : vb);
                    dst[(long)(gr + r) * 1024 + ei] = f2bf(v);
                } else {
                    outf[(long)(gr + r) * 1024 + gc] = v;
                }
            }
        }
}

// ---------------- flash attention, 1 wave / block, 32 q-rows, 32-key tiles ----------------
__global__ __launch_bounds__(64) void attn(
    const unsigned short* __restrict__ qbuf,
    const unsigned short* __restrict__ kbuf,
    const unsigned short* __restrict__ vbuf,
    unsigned short* __restrict__ obuf)
{
    __shared__ unsigned short Vs[32][72];  // V tile, padded
    __shared__ unsigned short Ps[32][40];  // P tile, padded
    int bh = blockIdx.y, qt = blockIdx.x;
    const unsigned short* Q = qbuf + (long)bh * 65536;
    const unsigned short* Kp = kbuf + (long)bh * 65536;
    const unsigned short* Vp = vbuf + (long)bh * 65536;
    unsigned short* O = obuf + (long)bh * 65536;
    int lane = threadIdx.x;
    int lrow = lane >> 4, lcol = lane & 15;
    int qbase = qt * 32;

    bf16x8 qf[2][2];
    #pragma unroll
    for (int qg = 0; qg < 2; ++qg)
        #pragma unroll
        for (int kc = 0; kc < 2; ++kc)
            qf[qg][kc] = ld_frag(Q + (long)(qbase + qg * 16 + lcol) * 64 + kc * 32 + lrow * 8);

    f32x4 acc[2][4] = {};
    float m_i[2][4], l_i[2][4];
    #pragma unroll
    for (int qg = 0; qg < 2; ++qg)
        #pragma unroll
        for (int r = 0; r < 4; ++r) { m_i[qg][r] = -__builtin_inff(); l_i[qg][r] = 0.f; }

    for (int kt = 0; kt <= qbase; kt += 32) {
        // --- S = Q K^T (scaled later) ---
        f32x4 s[2][2] = {};
        #pragma unroll
        for (int kg = 0; kg < 2; ++kg)
            #pragma unroll
            for (int kc = 0; kc < 2; ++kc) {
                bf16x8 kf = ld_frag(Kp + (long)(kt + kg * 16 + lcol) * 64 + kc * 32 + lrow * 8);
                s[0][kg] = __builtin_amdgcn_mfma_f32_16x16x32_bf16(qf[0][kc], kf, s[0][kg], 0, 0, 0);
                s[1][kg] = __builtin_amdgcn_mfma_f32_16x16x32_bf16(qf[1][kc], kf, s[1][kg], 0, 0, 0);
            }
        // --- stage V tile (coalesced) ---
        #pragma unroll
        for (int it = 0; it < 4; ++it) {
            int tt = it * 64 + lane;
            int row = tt >> 3, c8 = (tt & 7) * 8;
            *(uint4*)&Vs[row][c8] = *(const uint4*)(Vp + (long)(kt + row) * 64 + c8);
        }
        // --- mask + online softmax ---
        #pragma unroll
        for (int qg = 0; qg < 2; ++qg)
            #pragma unroll
            for (int r = 0; r < 4; ++r) {
                int q = qbase + qg * 16 + lrow * 4 + r;
                float s0 = s[qg][0][r] * 0.125f;
                float s1 = s[qg][1][r] * 0.125f;
                if (kt + lcol > q)      s0 = -__builtin_inff();
                if (kt + 16 + lcol > q) s1 = -__builtin_inff();
                float mx = fmaxf(s0, s1);
                #pragma unroll
                for (int d = 1; d < 16; d <<= 1) mx = fmaxf(mx, __shfl_xor(mx, d));
                float mnew = fmaxf(m_i[qg][r], mx);
                float alpha = __expf(m_i[qg][r] - mnew);
                float p0 = __expf(s0 - mnew);
                float p1 = __expf(s1 - mnew);
                float ps = p0 + p1;
                #pragma unroll
                for (int d = 1; d < 16; d <<= 1) ps += __shfl_xor(ps, d);
                l_i[qg][r] = l_i[qg][r] * alpha + ps;
                m_i[qg][r] = mnew;
                #pragma unroll
                for (int dg = 0; dg < 4; ++dg) acc[qg][dg][r] *= alpha;
                int prow = qg * 16 + lrow * 4 + r;
                Ps[prow][lcol]      = f2bf(p0);
                Ps[prow][16 + lcol] = f2bf(p1);
            }
        // --- O += P V ---
        bf16x8 pa[2];
        pa[0] = ld_frag(&Ps[lcol][lrow * 8]);
        pa[1] = ld_frag(&Ps[16 + lcol][lrow * 8]);
        #pragma unroll
        for (int dg = 0; dg < 4; ++dg) {
            union { unsigned short sh[8]; bf16x8 v; } vf;
            #pragma unroll
            for (int j = 0; j < 8; ++j) vf.sh[j] = Vs[lrow * 8 + j][dg * 16 + lcol];
            acc[0][dg] = __builtin_amdgcn_mfma_f32_16x16x32_bf16(pa[0], vf.v, acc[0][dg], 0, 0, 0);
            acc[1][dg] = __builtin_amdgcn_mfma_f32_16x16x32_bf16(pa[1], vf.v, acc[1][dg], 0, 0, 0);
        }
    }

    #pragma unroll
    for (int qg = 0; qg < 2; ++qg)
        #pragma unroll
        for (int r = 0; r < 4; ++r) {
            float inv = 1.f / l_i[qg][r];
            int q = qbase + qg * 16 + lrow * 4 + r;
            #pragma unroll
            for (int dg = 0; dg < 4; ++dg)
                O[(long)q * 64 + dg * 16 + lcol] = f2bf(acc[qg][dg][r] * inv);
        }
}

extern "C" void kernel_launch(void* const* d_in, const int* in_sizes, int n_in,
                              void* d_out, int out_size, void* d_ws, size_t ws_size,
                              hipStream_t stream) {
    const float* x    = (const float*)d_in[0];
    const float* Wqkv = (const float*)d_in[1];
    const float* bqkv = (const float*)d_in[2];
    const float* Wfc  = (const float*)d_in[3];
    const float* bfc  = (const float*)d_in[4];
    float* out = (float*)d_out;

    // ws layout (bf16 elements): xb/ob share (ob reused after GEMM1 consumes xb)
    unsigned short* ws    = (unsigned short*)d_ws;
    unsigned short* xb    = ws;                    // 4M  (also reused as ob)
    unsigned short* wqkvT = xb + (4u << 20);       // 3M
    unsigned short* wfcT  = wqkvT + (3u << 20);    // 1M
    unsigned short* qb    = wfcT + (1u << 20);     // 4M
    unsigned short* kb    = qb + (4u << 20);       // 4M
    unsigned short* vb    = kb + (4u << 20);       // 4M
    unsigned short* ob    = xb;                    // reuse: total 40 MB

    cvt_bf16<<<dim3(2048), dim3(256), 0, stream>>>(x, xb, (4 << 20) / 4);
    transpose_cvt<<<dim3(3072 / 32, 1024 / 32), dim3(32, 8), 0, stream>>>(Wqkv, wqkvT, 1024, 3072);
    transpose_cvt<<<dim3(1024 / 32, 1024 / 32), dim3(32, 8), 0, stream>>>(Wfc, wfcT, 1024, 1024);

    gemm64<0><<<dim3(48, 64), dim3(256), 0, stream>>>(xb, wqkvT, bqkv, qb, kb, vb, nullptr);
    attn<<<dim3(32, 64), dim3(64), 0, stream>>>(qb, kb, vb, ob);
    gemm64<1><<<dim3(16, 64), dim3(256), 0, stream>>>(ob, wfcT, bfc, nullptr, nullptr, nullptr, out);
}

// Round 3
// 199.638 us; speedup vs baseline: 1.0261x; 1.0261x over previous
//
#include <hip/hip_runtime.h>

// B=4, N=1024, E=1024, H=16, D=64.  bf16 MFMA (16x16x32), fp32 accum.
// Raw-reshape trick: per batch-head bh, Q/K/V head slab is the contiguous flat range
// [bh*65536, +65536) of the [b*n*e] buffer, viewed as [1024 n][64 d]. A separate
// transpose kernel builds V^T ([64 d][1024 n] per head) so attention's PV B-fragments
// are contiguous 16B global loads (no LDS V, no gather).

typedef __bf16 bf16x8 __attribute__((ext_vector_type(8)));
typedef float f32x4 __attribute__((ext_vector_type(4)));

__device__ __forceinline__ unsigned short f2bf(float f) {
    unsigned u = __float_as_uint(f);
    u += 0x7fffu + ((u >> 16) & 1u);   // round-to-nearest-even
    return (unsigned short)(u >> 16);
}

union FragU { uint4 u; bf16x8 v; };

__device__ __forceinline__ bf16x8 ld_frag(const unsigned short* p) {
    FragU x; x.u = *(const uint4*)p; return x.v;
}

__device__ __forceinline__ void gload_lds16(const void* g, void* l) {
    __builtin_amdgcn_global_load_lds(
        (const __attribute__((address_space(1))) void*)g,
        (__attribute__((address_space(3))) void*)l, 16, 0, 0);
}

// ---------------- fp32 -> bf16 elementwise ----------------
__global__ void cvt_bf16(const float* __restrict__ in, unsigned short* __restrict__ out, int n4) {
    int i = blockIdx.x * blockDim.x + threadIdx.x;
    int stride = gridDim.x * blockDim.x;
    for (; i < n4; i += stride) {
        float4 f = ((const float4*)in)[i];
        unsigned a = (unsigned)f2bf(f.x) | ((unsigned)f2bf(f.y) << 16);
        unsigned b = (unsigned)f2bf(f.z) | ((unsigned)f2bf(f.w) << 16);
        ((uint2*)out)[i] = make_uint2(a, b);
    }
}

// ---------------- fp32 [rows][cols] -> bf16 [cols][rows] ----------------
__global__ void transpose_cvt(const float* __restrict__ W, unsigned short* __restrict__ Wt,
                              int rows, int cols) {
    __shared__ float tile[32][33];
    int c0 = blockIdx.x * 32, r0 = blockIdx.y * 32;
    for (int i = threadIdx.y; i < 32; i += 8)
        tile[i][threadIdx.x] = W[(r0 + i) * cols + c0 + threadIdx.x];
    __syncthreads();
    for (int i = threadIdx.y; i < 32; i += 8)
        Wt[(c0 + i) * (long)rows + r0 + threadIdx.x] = f2bf(tile[threadIdx.x][i]);
}

// ---------------- per-head V transpose: [1024 n][64 d] -> [64 d][1024 n] ----------------
__global__ void transpose_v(const unsigned short* __restrict__ v,
                            unsigned short* __restrict__ vt) {
    __shared__ unsigned short tile[32][33];
    int bh = blockIdx.z;
    int n0 = blockIdx.x * 32, d0 = blockIdx.y * 32;
    const unsigned short* src = v + (long)bh * 65536;
    unsigned short* dst = vt + (long)bh * 65536;
    for (int i = threadIdx.y; i < 32; i += 8)
        tile[i][threadIdx.x] = src[(n0 + i) * 64 + d0 + threadIdx.x];
    __syncthreads();
    for (int i = threadIdx.y; i < 32; i += 8)
        dst[(d0 + i) * 1024 + n0 + threadIdx.x] = tile[threadIdx.x][i];
}

// ---------------- bf16 GEMM, 128x128 tile, global_load_lds staging ----------------
// C[M,N] = A[M,K] * Bt[N,K]^T + bias.
// MODE 0: N=3072 -> split q/k/v row-major flat.  MODE 1: N=1024 -> fp32 out.
template <int MODE>
__global__ __launch_bounds__(256) void gemm128(
    const unsigned short* __restrict__ A,    // [M,1024] bf16
    const unsigned short* __restrict__ Bt,   // [N,1024] bf16
    const float* __restrict__ bias,          // [N]
    unsigned short* __restrict__ qb,
    unsigned short* __restrict__ kb,
    unsigned short* __restrict__ vb,
    float* __restrict__ outf)
{
    const int K = 1024;
    __shared__ unsigned short As[4096];      // [128][32] linear (global_load_lds needs linear)
    __shared__ unsigned short Bs[4096];
    int t = threadIdx.x, lane = t & 63, w = t >> 6;
    int wm = w >> 1, wn = w & 1;             // 2x2 waves, 64x64 per wave
    int lrow = lane >> 4, lcol = lane & 15;
    int tn0 = blockIdx.x * 128, tm0 = blockIdx.y * 128;

    // staging geometry: tile is 8192B; wave w call c covers bytes [(w+4c)*1024, +1024)
    int seg0 = w * 1024;
    int seg1 = (w + 4) * 1024;
    int off0 = seg0 + lane * 16, off1 = seg1 + lane * 16;
    int r0 = off0 >> 6, cb0 = off0 & 63;     // row, byte-in-row (row = 64B = 32 bf16)
    int r1 = off1 >> 6, cb1 = off1 & 63;

    const char* gA = (const char*)A;
    const char* gB = (const char*)Bt;

    f32x4 acc[4][4] = {};

    for (int kt = 0; kt < K; kt += 32) {
        long kby = (long)kt * 2;
        gload_lds16(gA + (long)(tm0 + r0) * 2048 + kby + cb0, (char*)As + seg0);
        gload_lds16(gA + (long)(tm0 + r1) * 2048 + kby + cb1, (char*)As + seg1);
        gload_lds16(gB + (long)(tn0 + r0) * 2048 + kby + cb0, (char*)Bs + seg0);
        gload_lds16(gB + (long)(tn0 + r1) * 2048 + kby + cb1, (char*)Bs + seg1);
        __syncthreads();

        bf16x8 af[4], bfr[4];
        #pragma unroll
        for (int mi = 0; mi < 4; ++mi)
            af[mi] = ld_frag(As + (wm * 64 + mi * 16 + lcol) * 32 + lrow * 8);
        #pragma unroll
        for (int ni = 0; ni < 4; ++ni)
            bfr[ni] = ld_frag(Bs + (wn * 64 + ni * 16 + lcol) * 32 + lrow * 8);
        #pragma unroll
        for (int mi = 0; mi < 4; ++mi)
            #pragma unroll
            for (int ni = 0; ni < 4; ++ni)
                acc[mi][ni] = __builtin_amdgcn_mfma_f32_16x16x32_bf16(af[mi], bfr[ni], acc[mi][ni], 0, 0, 0);
        __syncthreads();
    }

    #pragma unroll
    for (int mi = 0; mi < 4; ++mi) {
        int gr0 = tm0 + wm * 64 + mi * 16 + lrow * 4;
        #pragma unroll
        for (int ni = 0; ni < 4; ++ni) {
            int gc = tn0 + wn * 64 + ni * 16 + lcol;
            float bv = bias[gc];
            if (MODE == 0) {
                int sec = gc >> 10, ei = gc & 1023;
                unsigned short* dst = sec == 0 ? qb : (sec == 1 ? kb : vb);
                #pragma unroll
                for (int r = 0; r < 4; ++r)
                    dst[(long)(gr0 + r) * 1024 + ei] = f2bf(acc[mi][ni][r] + bv);
            } else {
                #pragma unroll
                for (int r = 0; r < 4; ++r)
                    outf[(long)(gr0 + r) * 1024 + gc] = acc[mi][ni][r] + bv;
            }
        }
    }
}

// ---------------- flash attention, 1 wave / block, 32 q-rows, 32-key tiles ----------------
// V comes pre-transposed ([64 d][1024 n] per head) -> PV fragments straight from global.
__global__ __launch_bounds__(64) void attn(
    const unsigned short* __restrict__ qbuf,
    const unsigned short* __restrict__ kbuf,
    const unsigned short* __restrict__ vtbuf,
    unsigned short* __restrict__ obuf)
{
    __shared__ unsigned short Ps[32][40];  // P tile only
    int bh = blockIdx.y, qt = blockIdx.x;
    const unsigned short* Q  = qbuf + (long)bh * 65536;
    const unsigned short* Kp = kbuf + (long)bh * 65536;
    const unsigned short* VT = vtbuf + (long)bh * 65536;   // [64][1024]
    unsigned short* O = obuf + (long)bh * 65536;
    int lane = threadIdx.x;
    int lrow = lane >> 4, lcol = lane & 15;
    int qbase = qt * 32;

    bf16x8 qf[2][2];
    #pragma unroll
    for (int qg = 0; qg < 2; ++qg)
        #pragma unroll
        for (int kc = 0; kc < 2; ++kc)
            qf[qg][kc] = ld_frag(Q + (long)(qbase + qg * 16 + lcol) * 64 + kc * 32 + lrow * 8);

    f32x4 acc[2][4] = {};
    float m_i[2][4], l_i[2][4];
    #pragma unroll
    for (int qg = 0; qg < 2; ++qg)
        #pragma unroll
        for (int r = 0; r < 4; ++r) { m_i[qg][r] = -__builtin_inff(); l_i[qg][r] = 0.f; }

    for (int kt = 0; kt <= qbase; kt += 32) {
        // --- S = Q K^T ---
        f32x4 s[2][2] = {};
        __builtin_amdgcn_s_setprio(1);
        #pragma unroll
        for (int kg = 0; kg < 2; ++kg)
            #pragma unroll
            for (int kc = 0; kc < 2; ++kc) {
                bf16x8 kf = ld_frag(Kp + (long)(kt + kg * 16 + lcol) * 64 + kc * 32 + lrow * 8);
                s[0][kg] = __builtin_amdgcn_mfma_f32_16x16x32_bf16(qf[0][kc], kf, s[0][kg], 0, 0, 0);
                s[1][kg] = __builtin_amdgcn_mfma_f32_16x16x32_bf16(qf[1][kc], kf, s[1][kg], 0, 0, 0);
            }
        __builtin_amdgcn_s_setprio(0);
        // --- mask + online softmax ---
        #pragma unroll
        for (int qg = 0; qg < 2; ++qg)
            #pragma unroll
            for (int r = 0; r < 4; ++r) {
                int q = qbase + qg * 16 + lrow * 4 + r;
                float s0 = s[qg][0][r] * 0.125f;
                float s1 = s[qg][1][r] * 0.125f;
                if (kt + lcol > q)      s0 = -__builtin_inff();
                if (kt + 16 + lcol > q) s1 = -__builtin_inff();
                float mx = fmaxf(s0, s1);
                #pragma unroll
                for (int d = 1; d < 16; d <<= 1) mx = fmaxf(mx, __shfl_xor(mx, d));
                float mnew = fmaxf(m_i[qg][r], mx);
                float alpha = __expf(m_i[qg][r] - mnew);
                float p0 = __expf(s0 - mnew);
                float p1 = __expf(s1 - mnew);
                float ps = p0 + p1;
                #pragma unroll
                for (int d = 1; d < 16; d <<= 1) ps += __shfl_xor(ps, d);
                l_i[qg][r] = l_i[qg][r] * alpha + ps;
                m_i[qg][r] = mnew;
                #pragma unroll
                for (int dg = 0; dg < 4; ++dg) acc[qg][dg][r] *= alpha;
                int prow = qg * 16 + lrow * 4 + r;
                Ps[prow][lcol]      = f2bf(p0);
                Ps[prow][16 + lcol] = f2bf(p1);
            }
        // --- O += P V : V fragments straight from V^T in global ---
        bf16x8 pa[2];
        pa[0] = ld_frag(&Ps[lcol][lrow * 8]);
        pa[1] = ld_frag(&Ps[16 + lcol][lrow * 8]);
        __builtin_amdgcn_s_setprio(1);
        #pragma unroll
        for (int dg = 0; dg < 4; ++dg) {
            bf16x8 vf = ld_frag(VT + (long)(dg * 16 + lcol) * 1024 + kt + lrow * 8);
            acc[0][dg] = __builtin_amdgcn_mfma_f32_16x16x32_bf16(pa[0], vf, acc[0][dg], 0, 0, 0);
            acc[1][dg] = __builtin_amdgcn_mfma_f32_16x16x32_bf16(pa[1], vf, acc[1][dg], 0, 0, 0);
        }
        __builtin_amdgcn_s_setprio(0);
    }

    #pragma unroll
    for (int qg = 0; qg < 2; ++qg)
        #pragma unroll
        for (int r = 0; r < 4; ++r) {
            float inv = 1.f / l_i[qg][r];
            int q = qbase + qg * 16 + lrow * 4 + r;
            #pragma unroll
            for (int dg = 0; dg < 4; ++dg)
                O[(long)q * 64 + dg * 16 + lcol] = f2bf(acc[qg][dg][r] * inv);
        }
}

extern "C" void kernel_launch(void* const* d_in, const int* in_sizes, int n_in,
                              void* d_out, int out_size, void* d_ws, size_t ws_size,
                              hipStream_t stream) {
    const float* x    = (const float*)d_in[0];
    const float* Wqkv = (const float*)d_in[1];
    const float* bqkv = (const float*)d_in[2];
    const float* Wfc  = (const float*)d_in[3];
    const float* bfc  = (const float*)d_in[4];
    float* out = (float*)d_out;

    unsigned short* ws    = (unsigned short*)d_ws;
    unsigned short* xb    = ws;                    // 4M elems; dead after gemm<0>
    unsigned short* wqkvT = xb + (4u << 20);       // 3M
    unsigned short* wfcT  = wqkvT + (3u << 20);    // 1M
    unsigned short* qb    = wfcT + (1u << 20);     // 4M
    unsigned short* kb    = qb + (4u << 20);       // 4M
    unsigned short* vb    = kb + (4u << 20);       // 4M; dead after transpose_v
    unsigned short* vbT   = xb;                    // reuse xb
    unsigned short* ob    = vb;                    // reuse vb
    // total ws: 40 MB

    cvt_bf16<<<dim3(2048), dim3(256), 0, stream>>>(x, xb, (4 << 20) / 4);
    transpose_cvt<<<dim3(3072 / 32, 1024 / 32), dim3(32, 8), 0, stream>>>(Wqkv, wqkvT, 1024, 3072);
    transpose_cvt<<<dim3(1024 / 32, 1024 / 32), dim3(32, 8), 0, stream>>>(Wfc, wfcT, 1024, 1024);

    gemm128<0><<<dim3(24, 32), dim3(256), 0, stream>>>(xb, wqkvT, bqkv, qb, kb, vb, nullptr);
    transpose_v<<<dim3(32, 2, 64), dim3(32, 8), 0, stream>>>(vb, vbT);
    attn<<<dim3(32, 64), dim3(64), 0, stream>>>(qb, kb, vbT, ob);
    gemm128<1><<<dim3(8, 32), dim3(256), 0, stream>>>(ob, wfcT, bfc, nullptr, nullptr, nullptr, out);
}

// Round 4
// 158.627 us; speedup vs baseline: 1.2914x; 1.2585x over previous
//
#include <hip/hip_runtime.h>

// B=4, N=1024, E=1024, H=16, D=64.  bf16 MFMA (16x16x32), fp32 accum.
// Raw-reshape: per batch-head bh, Q/K slab = flat [bh*65536, +65536) viewed [1024 n][64 d].
// QKV GEMM epilogue writes V TRANSPOSED per head: vbT[bh*65536 + d*1024 + n]
// (mapping: bh=gr>>6, n=(gr&63)*16+(ei>>6), d=ei&63) so attention PV B-fragments are
// contiguous 16B global loads. Attention uses swapped QK^T (S^T=K*Q) so softmax is
// lane-local per q-row: 2 shuffles per 32-key tile instead of 64.

typedef __bf16 bf16x8 __attribute__((ext_vector_type(8)));
typedef float f32x4 __attribute__((ext_vector_type(4)));

__device__ __forceinline__ unsigned short f2bf(float f) {
    unsigned u = __float_as_uint(f);
    u += 0x7fffu + ((u >> 16) & 1u);   // round-to-nearest-even
    return (unsigned short)(u >> 16);
}

union FragU { uint4 u; bf16x8 v; };

__device__ __forceinline__ bf16x8 ld_frag(const unsigned short* p) {
    FragU x; x.u = *(const uint4*)p; return x.v;
}

__device__ __forceinline__ void gload_lds16(const void* g, void* l) {
    __builtin_amdgcn_global_load_lds(
        (const __attribute__((address_space(1))) void*)g,
        (__attribute__((address_space(3))) void*)l, 16, 0, 0);
}

// ---------------- fp32 -> bf16 elementwise ----------------
__global__ void cvt_bf16(const float* __restrict__ in, unsigned short* __restrict__ out, int n4) {
    int i = blockIdx.x * blockDim.x + threadIdx.x;
    int stride = gridDim.x * blockDim.x;
    for (; i < n4; i += stride) {
        float4 f = ((const float4*)in)[i];
        unsigned a = (unsigned)f2bf(f.x) | ((unsigned)f2bf(f.y) << 16);
        unsigned b = (unsigned)f2bf(f.z) | ((unsigned)f2bf(f.w) << 16);
        ((uint2*)out)[i] = make_uint2(a, b);
    }
}

// ---------------- fp32 [rows][cols] -> bf16 [cols][rows] ----------------
__global__ void transpose_cvt(const float* __restrict__ W, unsigned short* __restrict__ Wt,
                              int rows, int cols) {
    __shared__ float tile[32][33];
    int c0 = blockIdx.x * 32, r0 = blockIdx.y * 32;
    for (int i = threadIdx.y; i < 32; i += 8)
        tile[i][threadIdx.x] = W[(r0 + i) * cols + c0 + threadIdx.x];
    __syncthreads();
    for (int i = threadIdx.y; i < 32; i += 8)
        Wt[(c0 + i) * (long)rows + r0 + threadIdx.x] = f2bf(tile[threadIdx.x][i]);
}

// ---------------- bf16 GEMM, 128x128 tile, double-buffered global_load_lds ----------------
// C[M,N] = A[M,K] * Bt[N,K]^T + bias.
// MODE 0: N=3072 -> q/k row-major flat + V transposed per head.  MODE 1: N=1024 -> fp32 out.
template <int MODE>
__global__ __launch_bounds__(256) void gemm128(
    const unsigned short* __restrict__ A,    // [M,1024] bf16
    const unsigned short* __restrict__ Bt,   // [N,1024] bf16
    const float* __restrict__ bias,          // [N]
    unsigned short* __restrict__ qb,
    unsigned short* __restrict__ kb,
    unsigned short* __restrict__ vbT,        // [bh][64 d][1024 n]
    float* __restrict__ outf)
{
    const int K = 1024;
    __shared__ unsigned short As[2][4096];   // [128][32] linear per buffer
    __shared__ unsigned short Bs[2][4096];
    int t = threadIdx.x, lane = t & 63, w = t >> 6;
    int wm = w >> 1, wn = w & 1;             // 2x2 waves, 64x64 per wave
    int lrow = lane >> 4, lcol = lane & 15;
    int tn0 = blockIdx.x * 128, tm0 = blockIdx.y * 128;

    // staging geometry: tile is 8192B; wave w call c covers bytes [(w+4c)*1024, +1024)
    int seg0 = w * 1024;
    int seg1 = (w + 4) * 1024;
    int off0 = seg0 + lane * 16, off1 = seg1 + lane * 16;
    int r0 = off0 >> 6, cb0 = off0 & 63;     // row, byte-in-row (row = 64B = 32 bf16)
    int r1 = off1 >> 6, cb1 = off1 & 63;

    const char* gA = (const char*)A;
    const char* gB = (const char*)Bt;

    f32x4 acc[4][4] = {};

    auto STAGE = [&](int buf, int kt) {
        long kby = (long)kt * 2;
        gload_lds16(gA + (long)(tm0 + r0) * 2048 + kby + cb0, (char*)&As[buf][0] + seg0);
        gload_lds16(gA + (long)(tm0 + r1) * 2048 + kby + cb1, (char*)&As[buf][0] + seg1);
        gload_lds16(gB + (long)(tn0 + r0) * 2048 + kby + cb0, (char*)&Bs[buf][0] + seg0);
        gload_lds16(gB + (long)(tn0 + r1) * 2048 + kby + cb1, (char*)&Bs[buf][0] + seg1);
    };

    STAGE(0, 0);
    asm volatile("s_waitcnt vmcnt(0)");
    __syncthreads();

    int cur = 0;
    for (int kt = 0; kt < K; kt += 32) {
        if (kt + 32 < K) STAGE(cur ^ 1, kt + 32);   // prefetch next tile (flies under compute)

        bf16x8 af[4], bfr[4];
        #pragma unroll
        for (int mi = 0; mi < 4; ++mi)
            af[mi] = ld_frag(&As[cur][0] + (wm * 64 + mi * 16 + lcol) * 32 + lrow * 8);
        #pragma unroll
        for (int ni = 0; ni < 4; ++ni)
            bfr[ni] = ld_frag(&Bs[cur][0] + (wn * 64 + ni * 16 + lcol) * 32 + lrow * 8);
        #pragma unroll
        for (int mi = 0; mi < 4; ++mi)
            #pragma unroll
            for (int ni = 0; ni < 4; ++ni)
                acc[mi][ni] = __builtin_amdgcn_mfma_f32_16x16x32_bf16(af[mi], bfr[ni], acc[mi][ni], 0, 0, 0);

        __syncthreads();   // drains vmcnt too: next buffer staged, this buffer free to overwrite
        cur ^= 1;
    }

    #pragma unroll
    for (int mi = 0; mi < 4; ++mi) {
        int gr0 = tm0 + wm * 64 + mi * 16 + lrow * 4;
        #pragma unroll
        for (int ni = 0; ni < 4; ++ni) {
            int gc = tn0 + wn * 64 + ni * 16 + lcol;
            float bv = bias[gc];
            if (MODE == 0) {
                int sec = gc >> 10, ei = gc & 1023;
                if (sec < 2) {
                    unsigned short* dst = sec == 0 ? qb : kb;
                    #pragma unroll
                    for (int r = 0; r < 4; ++r)
                        dst[(long)(gr0 + r) * 1024 + ei] = f2bf(acc[mi][ni][r] + bv);
                } else {
                    // V^T: bh = gr>>6 (const over r), n = (gr&63)*16 + (ei>>6), d = ei&63
                    int d = ei & 63, c6 = ei >> 6;
                    long base = (long)(gr0 >> 6) * 65536 + (long)d * 1024 + c6;
                    int n0 = (gr0 & 63) * 16;
                    #pragma unroll
                    for (int r = 0; r < 4; ++r)
                        vbT[base + n0 + r * 16] = f2bf(acc[mi][ni][r] + bv);
                }
            } else {
                #pragma unroll
                for (int r = 0; r < 4; ++r)
                    outf[(long)(gr0 + r) * 1024 + gc] = acc[mi][ni][r] + bv;
            }
        }
    }
}

// ---------------- flash attention, swapped QK^T, 1 wave / block, 32 q-rows ----------------
// S^T = mfma(K,Q): lane holds S[k = kt+kg*16+lrow*4+reg][q = qbase+qg*16+lcol].
// Softmax is lane-local per q (2 shuffles across lrow partners).
// O^T = mfma(V^T, P): acc[qg][dg] holds O[d = dg*16+lrow*4+reg][q = lcol-based] — same q
// as the lane's m/l state, so rescale needs no cross-lane traffic.
__global__ __launch_bounds__(64) void attn(
    const unsigned short* __restrict__ qbuf,
    const unsigned short* __restrict__ kbuf,
    const unsigned short* __restrict__ vtbuf,
    unsigned short* __restrict__ obuf)
{
    __shared__ unsigned short Ps[32][40];   // P[q][k] tile, padded
    int bh = blockIdx.y, qt = blockIdx.x;
    const unsigned short* Q  = qbuf + (long)bh * 65536;
    const unsigned short* Kp = kbuf + (long)bh * 65536;
    const unsigned short* VT = vtbuf + (long)bh * 65536;   // [64 d][1024 n]
    unsigned short* O = obuf + (long)bh * 65536;
    int lane = threadIdx.x;
    int lrow = lane >> 4, lcol = lane & 15;
    int qbase = qt * 32;
    const float NEG = -__builtin_inff();

    // Q B-fragments: Q[q = qbase+qg*16+lcol][d = kc*32+lrow*8+j]
    bf16x8 qf[2][2];
    #pragma unroll
    for (int qg = 0; qg < 2; ++qg)
        #pragma unroll
        for (int kc = 0; kc < 2; ++kc)
            qf[qg][kc] = ld_frag(Q + (long)(qbase + qg * 16 + lcol) * 64 + kc * 32 + lrow * 8);

    // K A-fragments for first tile
    bf16x8 kf[2][2];
    #pragma unroll
    for (int kg = 0; kg < 2; ++kg)
        #pragma unroll
        for (int kc = 0; kc < 2; ++kc)
            kf[kg][kc] = ld_frag(Kp + (long)(kg * 16 + lcol) * 64 + kc * 32 + lrow * 8);

    f32x4 acc[2][4] = {};
    float m_i[2] = {NEG, NEG}, l_i[2] = {0.f, 0.f};   // per lane: q = qbase+qg*16+lcol

    for (int kt = 0;; kt += 32) {
        // --- S^T = K * Q ---
        f32x4 s[2][2] = {};
        __builtin_amdgcn_s_setprio(1);
        #pragma unroll
        for (int kg = 0; kg < 2; ++kg)
            #pragma unroll
            for (int kc = 0; kc < 2; ++kc) {
                s[0][kg] = __builtin_amdgcn_mfma_f32_16x16x32_bf16(kf[kg][kc], qf[0][kc], s[0][kg], 0, 0, 0);
                s[1][kg] = __builtin_amdgcn_mfma_f32_16x16x32_bf16(kf[kg][kc], qf[1][kc], s[1][kg], 0, 0, 0);
            }
        __builtin_amdgcn_s_setprio(0);

        bool more = kt < qbase;
        // prefetch next K tile (flies under softmax)
        bf16x8 kn[2][2];
        if (more) {
            #pragma unroll
            for (int kg = 0; kg < 2; ++kg)
                #pragma unroll
                for (int kc = 0; kc < 2; ++kc)
                    kn[kg][kc] = ld_frag(Kp + (long)(kt + 32 + kg * 16 + lcol) * 64 + kc * 32 + lrow * 8);
        }
        // V A-fragments for this tile: V^T[d = dg*16+lcol][k = kt+lrow*8+j]
        bf16x8 vf[4];
        #pragma unroll
        for (int dg = 0; dg < 4; ++dg)
            vf[dg] = ld_frag(VT + (long)(dg * 16 + lcol) * 1024 + kt + lrow * 8);

        // --- lane-local online softmax (q = lcol per qg) ---
        #pragma unroll
        for (int qg = 0; qg < 2; ++qg) {
            int q = qbase + qg * 16 + lcol;
            float tv[8];
            float mx = NEG;
            #pragma unroll
            for (int kg = 0; kg < 2; ++kg)
                #pragma unroll
                for (int r = 0; r < 4; ++r) {
                    int kglob = kt + kg * 16 + lrow * 4 + r;
                    float v = s[qg][kg][r] * 0.125f;
                    tv[kg * 4 + r] = kglob > q ? NEG : v;
                    mx = fmaxf(mx, tv[kg * 4 + r]);
                }
            mx = fmaxf(mx, __shfl_xor(mx, 16));
            mx = fmaxf(mx, __shfl_xor(mx, 32));
            float mnew = fmaxf(m_i[qg], mx);
            float alpha = __expf(m_i[qg] - mnew);
            float p[8], ps = 0.f;
            #pragma unroll
            for (int j = 0; j < 8; ++j) { p[j] = __expf(tv[j] - mnew); ps += p[j]; }
            // pack and write P[q][k]: 4 contiguous k per kg
            #pragma unroll
            for (int kg = 0; kg < 2; ++kg) {
                ushort4 pk;
                pk.x = f2bf(p[kg * 4 + 0]); pk.y = f2bf(p[kg * 4 + 1]);
                pk.z = f2bf(p[kg * 4 + 2]); pk.w = f2bf(p[kg * 4 + 3]);
                *(ushort4*)&Ps[qg * 16 + lcol][kg * 16 + lrow * 4] = pk;
            }
            ps += __shfl_xor(ps, 16);
            ps += __shfl_xor(ps, 32);
            l_i[qg] = l_i[qg] * alpha + ps;
            m_i[qg] = mnew;
            #pragma unroll
            for (int dg = 0; dg < 4; ++dg)
                #pragma unroll
                for (int r = 0; r < 4; ++r)
                    acc[qg][dg][r] *= alpha;
        }

        // --- O^T += V^T * P ---
        bf16x8 pb[2];
        pb[0] = ld_frag(&Ps[lcol][lrow * 8]);
        pb[1] = ld_frag(&Ps[16 + lcol][lrow * 8]);
        __builtin_amdgcn_s_setprio(1);
        #pragma unroll
        for (int dg = 0; dg < 4; ++dg) {
            acc[0][dg] = __builtin_amdgcn_mfma_f32_16x16x32_bf16(vf[dg], pb[0], acc[0][dg], 0, 0, 0);
            acc[1][dg] = __builtin_amdgcn_mfma_f32_16x16x32_bf16(vf[dg], pb[1], acc[1][dg], 0, 0, 0);
        }
        __builtin_amdgcn_s_setprio(0);

        if (!more) break;
        #pragma unroll
        for (int kg = 0; kg < 2; ++kg)
            #pragma unroll
            for (int kc = 0; kc < 2; ++kc)
                kf[kg][kc] = kn[kg][kc];
    }

    // epilogue: O[q][d], q = qbase+qg*16+lcol, d = dg*16+lrow*4+reg (4 consecutive)
    #pragma unroll
    for (int qg = 0; qg < 2; ++qg) {
        float inv = 1.f / l_i[qg];
        int q = qbase + qg * 16 + lcol;
        #pragma unroll
        for (int dg = 0; dg < 4; ++dg) {
            ushort4 pk;
            pk.x = f2bf(acc[qg][dg][0] * inv);
            pk.y = f2bf(acc[qg][dg][1] * inv);
            pk.z = f2bf(acc[qg][dg][2] * inv);
            pk.w = f2bf(acc[qg][dg][3] * inv);
            *(ushort4*)&O[(long)q * 64 + dg * 16 + lrow * 4] = pk;
        }
    }
}

extern "C" void kernel_launch(void* const* d_in, const int* in_sizes, int n_in,
                              void* d_out, int out_size, void* d_ws, size_t ws_size,
                              hipStream_t stream) {
    const float* x    = (const float*)d_in[0];
    const float* Wqkv = (const float*)d_in[1];
    const float* bqkv = (const float*)d_in[2];
    const float* Wfc  = (const float*)d_in[3];
    const float* bfc  = (const float*)d_in[4];
    float* out = (float*)d_out;

    unsigned short* ws    = (unsigned short*)d_ws;
    unsigned short* xb    = ws;                    // 4M elems; dead after gemm<0>
    unsigned short* wqkvT = xb + (4u << 20);       // 3M
    unsigned short* wfcT  = wqkvT + (3u << 20);    // 1M
    unsigned short* qb    = wfcT + (1u << 20);     // 4M
    unsigned short* kb    = qb + (4u << 20);       // 4M
    unsigned short* vbT   = kb + (4u << 20);       // 4M
    unsigned short* ob    = xb;                    // reuse xb
    // total ws: 40 MB

    cvt_bf16<<<dim3(2048), dim3(256), 0, stream>>>(x, xb, (4 << 20) / 4);
    transpose_cvt<<<dim3(3072 / 32, 1024 / 32), dim3(32, 8), 0, stream>>>(Wqkv, wqkvT, 1024, 3072);
    transpose_cvt<<<dim3(1024 / 32, 1024 / 32), dim3(32, 8), 0, stream>>>(Wfc, wfcT, 1024, 1024);

    gemm128<0><<<dim3(24, 32), dim3(256), 0, stream>>>(xb, wqkvT, bqkv, qb, kb, vbT, nullptr);
    attn<<<dim3(32, 64), dim3(64), 0, stream>>>(qb, kb, vbT, ob);
    gemm128<1><<<dim3(8, 32), dim3(256), 0, stream>>>(ob, wfcT, bfc, nullptr, nullptr, nullptr, out);
}

// Round 5
// 156.880 us; speedup vs baseline: 1.3058x; 1.0111x over previous
//
#include <hip/hip_runtime.h>

// B=4, N=1024, E=1024, H=16, D=64.  bf16 MFMA (16x16x32), fp32 accum.
// Raw-reshape: per batch-head bh, Q/K slab = flat [bh*65536, +65536) viewed [1024 n][64 d].
// QKV GEMM epilogue writes V TRANSPOSED per head: vbT[bh*65536 + d*1024 + n]
// (mapping: bh=gr>>6, n=(gr&63)*16+(ei>>6), d=ei&63) so attention PV B-fragments are
// contiguous 16B global loads. Attention: swapped QK^T (S^T=K*Q, lane-local softmax)
// + SPLIT-K across 4 waves per block (private m/l/acc, LDS merge) for occupancy.

typedef __bf16 bf16x8 __attribute__((ext_vector_type(8)));
typedef float f32x4 __attribute__((ext_vector_type(4)));

__device__ __forceinline__ unsigned short f2bf(float f) {
    unsigned u = __float_as_uint(f);
    u += 0x7fffu + ((u >> 16) & 1u);   // round-to-nearest-even
    return (unsigned short)(u >> 16);
}

union FragU { uint4 u; bf16x8 v; };

__device__ __forceinline__ bf16x8 ld_frag(const unsigned short* p) {
    FragU x; x.u = *(const uint4*)p; return x.v;
}

__device__ __forceinline__ void gload_lds16(const void* g, void* l) {
    __builtin_amdgcn_global_load_lds(
        (const __attribute__((address_space(1))) void*)g,
        (__attribute__((address_space(3))) void*)l, 16, 0, 0);
}

// ---------------- fp32 -> bf16 elementwise ----------------
__global__ void cvt_bf16(const float* __restrict__ in, unsigned short* __restrict__ out, int n4) {
    int i = blockIdx.x * blockDim.x + threadIdx.x;
    int stride = gridDim.x * blockDim.x;
    for (; i < n4; i += stride) {
        float4 f = ((const float4*)in)[i];
        unsigned a = (unsigned)f2bf(f.x) | ((unsigned)f2bf(f.y) << 16);
        unsigned b = (unsigned)f2bf(f.z) | ((unsigned)f2bf(f.w) << 16);
        ((uint2*)out)[i] = make_uint2(a, b);
    }
}

// ---------------- fp32 [rows][cols] -> bf16 [cols][rows] ----------------
__global__ void transpose_cvt(const float* __restrict__ W, unsigned short* __restrict__ Wt,
                              int rows, int cols) {
    __shared__ float tile[32][33];
    int c0 = blockIdx.x * 32, r0 = blockIdx.y * 32;
    for (int i = threadIdx.y; i < 32; i += 8)
        tile[i][threadIdx.x] = W[(r0 + i) * cols + c0 + threadIdx.x];
    __syncthreads();
    for (int i = threadIdx.y; i < 32; i += 8)
        Wt[(c0 + i) * (long)rows + r0 + threadIdx.x] = f2bf(tile[threadIdx.x][i]);
}

// ---------------- bf16 GEMM, 128x128 tile, double-buffered global_load_lds ----------------
template <int MODE>
__global__ __launch_bounds__(256) void gemm128(
    const unsigned short* __restrict__ A,    // [M,1024] bf16
    const unsigned short* __restrict__ Bt,   // [N,1024] bf16
    const float* __restrict__ bias,          // [N]
    unsigned short* __restrict__ qb,
    unsigned short* __restrict__ kb,
    unsigned short* __restrict__ vbT,        // [bh][64 d][1024 n]
    float* __restrict__ outf)
{
    const int K = 1024;
    __shared__ unsigned short As[2][4096];   // [128][32] linear per buffer
    __shared__ unsigned short Bs[2][4096];
    int t = threadIdx.x, lane = t & 63, w = t >> 6;
    int wm = w >> 1, wn = w & 1;             // 2x2 waves, 64x64 per wave
    int lrow = lane >> 4, lcol = lane & 15;
    int tn0 = blockIdx.x * 128, tm0 = blockIdx.y * 128;

    int seg0 = w * 1024;
    int seg1 = (w + 4) * 1024;
    int off0 = seg0 + lane * 16, off1 = seg1 + lane * 16;
    int r0 = off0 >> 6, cb0 = off0 & 63;
    int r1 = off1 >> 6, cb1 = off1 & 63;

    const char* gA = (const char*)A;
    const char* gB = (const char*)Bt;

    f32x4 acc[4][4] = {};

    auto STAGE = [&](int buf, int kt) {
        long kby = (long)kt * 2;
        gload_lds16(gA + (long)(tm0 + r0) * 2048 + kby + cb0, (char*)&As[buf][0] + seg0);
        gload_lds16(gA + (long)(tm0 + r1) * 2048 + kby + cb1, (char*)&As[buf][0] + seg1);
        gload_lds16(gB + (long)(tn0 + r0) * 2048 + kby + cb0, (char*)&Bs[buf][0] + seg0);
        gload_lds16(gB + (long)(tn0 + r1) * 2048 + kby + cb1, (char*)&Bs[buf][0] + seg1);
    };

    STAGE(0, 0);
    asm volatile("s_waitcnt vmcnt(0)");
    __syncthreads();

    int cur = 0;
    for (int kt = 0; kt < K; kt += 32) {
        if (kt + 32 < K) STAGE(cur ^ 1, kt + 32);

        bf16x8 af[4], bfr[4];
        #pragma unroll
        for (int mi = 0; mi < 4; ++mi)
            af[mi] = ld_frag(&As[cur][0] + (wm * 64 + mi * 16 + lcol) * 32 + lrow * 8);
        #pragma unroll
        for (int ni = 0; ni < 4; ++ni)
            bfr[ni] = ld_frag(&Bs[cur][0] + (wn * 64 + ni * 16 + lcol) * 32 + lrow * 8);
        #pragma unroll
        for (int mi = 0; mi < 4; ++mi)
            #pragma unroll
            for (int ni = 0; ni < 4; ++ni)
                acc[mi][ni] = __builtin_amdgcn_mfma_f32_16x16x32_bf16(af[mi], bfr[ni], acc[mi][ni], 0, 0, 0);

        __syncthreads();
        cur ^= 1;
    }

    #pragma unroll
    for (int mi = 0; mi < 4; ++mi) {
        int gr0 = tm0 + wm * 64 + mi * 16 + lrow * 4;
        #pragma unroll
        for (int ni = 0; ni < 4; ++ni) {
            int gc = tn0 + wn * 64 + ni * 16 + lcol;
            float bv = bias[gc];
            if (MODE == 0) {
                int sec = gc >> 10, ei = gc & 1023;
                if (sec < 2) {
                    unsigned short* dst = sec == 0 ? qb : kb;
                    #pragma unroll
                    for (int r = 0; r < 4; ++r)
                        dst[(long)(gr0 + r) * 1024 + ei] = f2bf(acc[mi][ni][r] + bv);
                } else {
                    int d = ei & 63, c6 = ei >> 6;
                    long base = (long)(gr0 >> 6) * 65536 + (long)d * 1024 + c6;
                    int n0 = (gr0 & 63) * 16;
                    #pragma unroll
                    for (int r = 0; r < 4; ++r)
                        vbT[base + n0 + r * 16] = f2bf(acc[mi][ni][r] + bv);
                }
            } else {
                #pragma unroll
                for (int r = 0; r < 4; ++r)
                    outf[(long)(gr0 + r) * 1024 + gc] = acc[mi][ni][r] + bv;
            }
        }
    }
}

// ---------------- flash attention: swapped QK^T + 4-wave split-K + LDS merge ----------------
// Wave w handles key-tiles w, w+4, ... of this block's 32-row q-tile, with private
// (m, l, acc). Merge: O = sum_w e^{m_w-M} acc_w / sum_w e^{m_w-M} l_w.
__global__ __launch_bounds__(256) void attn(
    const unsigned short* __restrict__ qbuf,
    const unsigned short* __restrict__ kbuf,
    const unsigned short* __restrict__ vtbuf,
    unsigned short* __restrict__ obuf)
{
    // smem: during loop, per-wave P tiles [4][32][40] shorts (10,240 B).
    // after barrier, reused as merge buffers: accS [4][32][68] f32 (34,816 B) +
    // mS [4][32] f32 (512 B) + lS [4][32] f32 (512 B).
    __shared__ char smem[4 * 32 * 68 * 4 + 512 + 512] __attribute__((aligned(16)));
    unsigned short (*Ps)[32][40] = (unsigned short (*)[32][40])smem;
    float* accS = (float*)smem;                       // [4][32][68]
    float* mS = (float*)(smem + 4 * 32 * 68 * 4);     // [4][32]
    float* lS = mS + 128;                              // [4][32]

    int bh = blockIdx.y, qt = blockIdx.x;
    const unsigned short* Q  = qbuf + (long)bh * 65536;
    const unsigned short* Kp = kbuf + (long)bh * 65536;
    const unsigned short* VT = vtbuf + (long)bh * 65536;   // [64 d][1024 n]
    unsigned short* O = obuf + (long)bh * 65536;
    int t = threadIdx.x, lane = t & 63, w = t >> 6;
    int lrow = lane >> 4, lcol = lane & 15;
    int qbase = qt * 32;
    int T = qt + 1;                                    // number of 32-key tiles
    const float NEG = -__builtin_inff();

    // Q B-fragments (same for all waves; L2-hot)
    bf16x8 qf[2][2];
    #pragma unroll
    for (int qg = 0; qg < 2; ++qg)
        #pragma unroll
        for (int kc = 0; kc < 2; ++kc)
            qf[qg][kc] = ld_frag(Q + (long)(qbase + qg * 16 + lcol) * 64 + kc * 32 + lrow * 8);

    f32x4 acc[2][4] = {};
    float m_i[2] = {NEG, NEG}, l_i[2] = {0.f, 0.f};

    if (w < T) {
        // K fragments for first owned tile
        int kt = w * 32;
        bf16x8 kf[2][2];
        #pragma unroll
        for (int kg = 0; kg < 2; ++kg)
            #pragma unroll
            for (int kc = 0; kc < 2; ++kc)
                kf[kg][kc] = ld_frag(Kp + (long)(kt + kg * 16 + lcol) * 64 + kc * 32 + lrow * 8);

        for (;; kt += 128) {
            // --- S^T = K * Q ---
            f32x4 s[2][2] = {};
            __builtin_amdgcn_s_setprio(1);
            #pragma unroll
            for (int kg = 0; kg < 2; ++kg)
                #pragma unroll
                for (int kc = 0; kc < 2; ++kc) {
                    s[0][kg] = __builtin_amdgcn_mfma_f32_16x16x32_bf16(kf[kg][kc], qf[0][kc], s[0][kg], 0, 0, 0);
                    s[1][kg] = __builtin_amdgcn_mfma_f32_16x16x32_bf16(kf[kg][kc], qf[1][kc], s[1][kg], 0, 0, 0);
                }
            __builtin_amdgcn_s_setprio(0);

            bool more = kt + 128 < T * 32;
            // prefetch next owned K tile (flies under softmax)
            bf16x8 kn[2][2];
            if (more) {
                #pragma unroll
                for (int kg = 0; kg < 2; ++kg)
                    #pragma unroll
                    for (int kc = 0; kc < 2; ++kc)
                        kn[kg][kc] = ld_frag(Kp + (long)(kt + 128 + kg * 16 + lcol) * 64 + kc * 32 + lrow * 8);
            }
            // V A-fragments for this tile
            bf16x8 vf[4];
            #pragma unroll
            for (int dg = 0; dg < 4; ++dg)
                vf[dg] = ld_frag(VT + (long)(dg * 16 + lcol) * 1024 + kt + lrow * 8);

            // --- lane-local online softmax ---
            #pragma unroll
            for (int qg = 0; qg < 2; ++qg) {
                int q = qbase + qg * 16 + lcol;
                float tv[8];
                float mx = NEG;
                #pragma unroll
                for (int kg = 0; kg < 2; ++kg)
                    #pragma unroll
                    for (int r = 0; r < 4; ++r) {
                        int kglob = kt + kg * 16 + lrow * 4 + r;
                        float v = s[qg][kg][r] * 0.125f;
                        tv[kg * 4 + r] = kglob > q ? NEG : v;
                        mx = fmaxf(mx, tv[kg * 4 + r]);
                    }
                mx = fmaxf(mx, __shfl_xor(mx, 16));
                mx = fmaxf(mx, __shfl_xor(mx, 32));
                float mnew = fmaxf(m_i[qg], mx);
                float alpha = __expf(m_i[qg] - mnew);
                float p[8], ps = 0.f;
                #pragma unroll
                for (int j = 0; j < 8; ++j) { p[j] = __expf(tv[j] - mnew); ps += p[j]; }
                #pragma unroll
                for (int kg = 0; kg < 2; ++kg) {
                    ushort4 pk;
                    pk.x = f2bf(p[kg * 4 + 0]); pk.y = f2bf(p[kg * 4 + 1]);
                    pk.z = f2bf(p[kg * 4 + 2]); pk.w = f2bf(p[kg * 4 + 3]);
                    *(ushort4*)&Ps[w][qg * 16 + lcol][kg * 16 + lrow * 4] = pk;
                }
                ps += __shfl_xor(ps, 16);
                ps += __shfl_xor(ps, 32);
                l_i[qg] = l_i[qg] * alpha + ps;
                m_i[qg] = mnew;
                #pragma unroll
                for (int dg = 0; dg < 4; ++dg)
                    #pragma unroll
                    for (int r = 0; r < 4; ++r)
                        acc[qg][dg][r] *= alpha;
            }

            // --- O^T += V^T * P ---
            bf16x8 pb[2];
            pb[0] = ld_frag(&Ps[w][lcol][lrow * 8]);
            pb[1] = ld_frag(&Ps[w][16 + lcol][lrow * 8]);
            __builtin_amdgcn_s_setprio(1);
            #pragma unroll
            for (int dg = 0; dg < 4; ++dg) {
                acc[0][dg] = __builtin_amdgcn_mfma_f32_16x16x32_bf16(vf[dg], pb[0], acc[0][dg], 0, 0, 0);
                acc[1][dg] = __builtin_amdgcn_mfma_f32_16x16x32_bf16(vf[dg], pb[1], acc[1][dg], 0, 0, 0);
            }
            __builtin_amdgcn_s_setprio(0);

            if (!more) break;
            #pragma unroll
            for (int kg = 0; kg < 2; ++kg)
                #pragma unroll
                for (int kc = 0; kc < 2; ++kc)
                    kf[kg][kc] = kn[kg][kc];
        }
    }

    // --- merge 4 wave-partials through LDS ---
    __syncthreads();   // all Ps usage done; smem becomes merge buffers
    #pragma unroll
    for (int qg = 0; qg < 2; ++qg) {
        int q = qg * 16 + lcol;
        if (lrow == 0) { mS[w * 32 + q] = m_i[qg]; lS[w * 32 + q] = l_i[qg]; }
        #pragma unroll
        for (int dg = 0; dg < 4; ++dg)
            *(f32x4*)&accS[(w * 32 + q) * 68 + dg * 16 + lrow * 4] = acc[qg][dg];
    }
    __syncthreads();

    int qq = t >> 3, d0 = (t & 7) * 8;
    float m0 = mS[qq], m1 = mS[32 + qq], m2 = mS[64 + qq], m3 = mS[96 + qq];
    float M = fmaxf(fmaxf(m0, m1), fmaxf(m2, m3));
    float e0 = __expf(m0 - M), e1 = __expf(m1 - M), e2 = __expf(m2 - M), e3 = __expf(m3 - M);
    float L = e0 * lS[qq] + e1 * lS[32 + qq] + e2 * lS[64 + qq] + e3 * lS[96 + qq];
    float inv = 1.f / L;
    const float* a0 = &accS[qq * 68 + d0];
    const float* a1 = &accS[(32 + qq) * 68 + d0];
    const float* a2 = &accS[(64 + qq) * 68 + d0];
    const float* a3 = &accS[(96 + qq) * 68 + d0];
    unsigned short h[8];
    #pragma unroll
    for (int j = 0; j < 8; ++j)
        h[j] = f2bf((e0 * a0[j] + e1 * a1[j] + e2 * a2[j] + e3 * a3[j]) * inv);
    uint4 pk;
    pk.x = (unsigned)h[0] | ((unsigned)h[1] << 16);
    pk.y = (unsigned)h[2] | ((unsigned)h[3] << 16);
    pk.z = (unsigned)h[4] | ((unsigned)h[5] << 16);
    pk.w = (unsigned)h[6] | ((unsigned)h[7] << 16);
    *(uint4*)&O[(long)(qbase + qq) * 64 + d0] = pk;
}

extern "C" void kernel_launch(void* const* d_in, const int* in_sizes, int n_in,
                              void* d_out, int out_size, void* d_ws, size_t ws_size,
                              hipStream_t stream) {
    const float* x    = (const float*)d_in[0];
    const float* Wqkv = (const float*)d_in[1];
    const float* bqkv = (const float*)d_in[2];
    const float* Wfc  = (const float*)d_in[3];
    const float* bfc  = (const float*)d_in[4];
    float* out = (float*)d_out;

    unsigned short* ws    = (unsigned short*)d_ws;
    unsigned short* xb    = ws;                    // 4M elems; dead after gemm<0>
    unsigned short* wqkvT = xb + (4u << 20);       // 3M
    unsigned short* wfcT  = wqkvT + (3u << 20);    // 1M
    unsigned short* qb    = wfcT + (1u << 20);     // 4M
    unsigned short* kb    = qb + (4u << 20);       // 4M
    unsigned short* vbT   = kb + (4u << 20);       // 4M
    unsigned short* ob    = xb;                    // reuse xb
    // total ws: 40 MB

    cvt_bf16<<<dim3(2048), dim3(256), 0, stream>>>(x, xb, (4 << 20) / 4);
    transpose_cvt<<<dim3(3072 / 32, 1024 / 32), dim3(32, 8), 0, stream>>>(Wqkv, wqkvT, 1024, 3072);
    transpose_cvt<<<dim3(1024 / 32, 1024 / 32), dim3(32, 8), 0, stream>>>(Wfc, wfcT, 1024, 1024);

    gemm128<0><<<dim3(24, 32), dim3(256), 0, stream>>>(xb, wqkvT, bqkv, qb, kb, vbT, nullptr);
    attn<<<dim3(32, 64), dim3(256), 0, stream>>>(qb, kb, vbT, ob);
    gemm128<1><<<dim3(8, 32), dim3(256), 0, stream>>>(ob, wfcT, bfc, nullptr, nullptr, nullptr, out);
}

// Round 6
// 134.504 us; speedup vs baseline: 1.5230x; 1.1664x over previous
//
#include <hip/hip_runtime.h>

// B=4, N=1024, E=1024, H=16, D=64.  bf16 MFMA (16x16x32), fp32 accum.
// Raw-reshape: per batch-head bh, Q/K slab = flat [bh*65536, +65536) viewed [1024 n][64 d].
// QKV GEMM epilogue writes V TRANSPOSED per head: vbT[bh*65536 + d*1024 + n]
// (mapping: bh=gr>>6, n=(gr&63)*16+(ei>>6), d=ei&63) so attention PV B-fragments are
// contiguous 16B global loads. Attention: swapped QK^T (S^T=K*Q, lane-local softmax),
// 4-wave split-K with LDS merge, and CAUSAL PAIRING: block j handles q-tiles {j, 31-j}
// sequentially so every block owns exactly 33 key-tiles (load balance -> occupancy).

typedef __bf16 bf16x8 __attribute__((ext_vector_type(8)));
typedef float f32x4 __attribute__((ext_vector_type(4)));

__device__ __forceinline__ unsigned short f2bf(float f) {
    unsigned u = __float_as_uint(f);
    u += 0x7fffu + ((u >> 16) & 1u);   // round-to-nearest-even
    return (unsigned short)(u >> 16);
}

union FragU { uint4 u; bf16x8 v; };

__device__ __forceinline__ bf16x8 ld_frag(const unsigned short* p) {
    FragU x; x.u = *(const uint4*)p; return x.v;
}

__device__ __forceinline__ void gload_lds16(const void* g, void* l) {
    __builtin_amdgcn_global_load_lds(
        (const __attribute__((address_space(1))) void*)g,
        (__attribute__((address_space(3))) void*)l, 16, 0, 0);
}

// ---------------- fp32 -> bf16 elementwise ----------------
__global__ void cvt_bf16(const float* __restrict__ in, unsigned short* __restrict__ out, int n4) {
    int i = blockIdx.x * blockDim.x + threadIdx.x;
    int stride = gridDim.x * blockDim.x;
    for (; i < n4; i += stride) {
        float4 f = ((const float4*)in)[i];
        unsigned a = (unsigned)f2bf(f.x) | ((unsigned)f2bf(f.y) << 16);
        unsigned b = (unsigned)f2bf(f.z) | ((unsigned)f2bf(f.w) << 16);
        ((uint2*)out)[i] = make_uint2(a, b);
    }
}

// ---------------- fp32 [rows][cols] -> bf16 [cols][rows] ----------------
__global__ void transpose_cvt(const float* __restrict__ W, unsigned short* __restrict__ Wt,
                              int rows, int cols) {
    __shared__ float tile[32][33];
    int c0 = blockIdx.x * 32, r0 = blockIdx.y * 32;
    for (int i = threadIdx.y; i < 32; i += 8)
        tile[i][threadIdx.x] = W[(r0 + i) * cols + c0 + threadIdx.x];
    __syncthreads();
    for (int i = threadIdx.y; i < 32; i += 8)
        Wt[(c0 + i) * (long)rows + r0 + threadIdx.x] = f2bf(tile[threadIdx.x][i]);
}

// ---------------- bf16 GEMM, 128x128 tile, double-buffered global_load_lds ----------------
template <int MODE>
__global__ __launch_bounds__(256) void gemm128(
    const unsigned short* __restrict__ A,    // [M,1024] bf16
    const unsigned short* __restrict__ Bt,   // [N,1024] bf16
    const float* __restrict__ bias,          // [N]
    unsigned short* __restrict__ qb,
    unsigned short* __restrict__ kb,
    unsigned short* __restrict__ vbT,        // [bh][64 d][1024 n]
    float* __restrict__ outf)
{
    const int K = 1024;
    __shared__ unsigned short As[2][4096];   // [128][32] linear per buffer
    __shared__ unsigned short Bs[2][4096];
    int t = threadIdx.x, lane = t & 63, w = t >> 6;
    int wm = w >> 1, wn = w & 1;             // 2x2 waves, 64x64 per wave
    int lrow = lane >> 4, lcol = lane & 15;
    int tn0 = blockIdx.x * 128, tm0 = blockIdx.y * 128;

    int seg0 = w * 1024;
    int seg1 = (w + 4) * 1024;
    int off0 = seg0 + lane * 16, off1 = seg1 + lane * 16;
    int r0 = off0 >> 6, cb0 = off0 & 63;
    int r1 = off1 >> 6, cb1 = off1 & 63;

    const char* gA = (const char*)A;
    const char* gB = (const char*)Bt;

    f32x4 acc[4][4] = {};

    auto STAGE = [&](int buf, int kt) {
        long kby = (long)kt * 2;
        gload_lds16(gA + (long)(tm0 + r0) * 2048 + kby + cb0, (char*)&As[buf][0] + seg0);
        gload_lds16(gA + (long)(tm0 + r1) * 2048 + kby + cb1, (char*)&As[buf][0] + seg1);
        gload_lds16(gB + (long)(tn0 + r0) * 2048 + kby + cb0, (char*)&Bs[buf][0] + seg0);
        gload_lds16(gB + (long)(tn0 + r1) * 2048 + kby + cb1, (char*)&Bs[buf][0] + seg1);
    };

    STAGE(0, 0);
    asm volatile("s_waitcnt vmcnt(0)");
    __syncthreads();

    int cur = 0;
    for (int kt = 0; kt < K; kt += 32) {
        if (kt + 32 < K) STAGE(cur ^ 1, kt + 32);

        bf16x8 af[4], bfr[4];
        #pragma unroll
        for (int mi = 0; mi < 4; ++mi)
            af[mi] = ld_frag(&As[cur][0] + (wm * 64 + mi * 16 + lcol) * 32 + lrow * 8);
        #pragma unroll
        for (int ni = 0; ni < 4; ++ni)
            bfr[ni] = ld_frag(&Bs[cur][0] + (wn * 64 + ni * 16 + lcol) * 32 + lrow * 8);
        #pragma unroll
        for (int mi = 0; mi < 4; ++mi)
            #pragma unroll
            for (int ni = 0; ni < 4; ++ni)
                acc[mi][ni] = __builtin_amdgcn_mfma_f32_16x16x32_bf16(af[mi], bfr[ni], acc[mi][ni], 0, 0, 0);

        __syncthreads();
        cur ^= 1;
    }

    #pragma unroll
    for (int mi = 0; mi < 4; ++mi) {
        int gr0 = tm0 + wm * 64 + mi * 16 + lrow * 4;
        #pragma unroll
        for (int ni = 0; ni < 4; ++ni) {
            int gc = tn0 + wn * 64 + ni * 16 + lcol;
            float bv = bias[gc];
            if (MODE == 0) {
                int sec = gc >> 10, ei = gc & 1023;
                if (sec < 2) {
                    unsigned short* dst = sec == 0 ? qb : kb;
                    #pragma unroll
                    for (int r = 0; r < 4; ++r)
                        dst[(long)(gr0 + r) * 1024 + ei] = f2bf(acc[mi][ni][r] + bv);
                } else {
                    int d = ei & 63, c6 = ei >> 6;
                    long base = (long)(gr0 >> 6) * 65536 + (long)d * 1024 + c6;
                    int n0 = (gr0 & 63) * 16;
                    #pragma unroll
                    for (int r = 0; r < 4; ++r)
                        vbT[base + n0 + r * 16] = f2bf(acc[mi][ni][r] + bv);
                }
            } else {
                #pragma unroll
                for (int r = 0; r < 4; ++r)
                    outf[(long)(gr0 + r) * 1024 + gc] = acc[mi][ni][r] + bv;
            }
        }
    }
}

// ---------------- flash attention: swapped QK^T + 4-wave split-K + causal pairing ----------------
// Block (j, bh) processes q-tiles {j, 31-j} sequentially; each q-tile split-K over 4 waves
// (wave w owns key-tiles w, w+4, ...). Merge: O = sum_w e^{m_w-M} acc_w / sum_w e^{m_w-M} l_w.
__global__ __launch_bounds__(256) void attn(
    const unsigned short* __restrict__ qbuf,
    const unsigned short* __restrict__ kbuf,
    const unsigned short* __restrict__ vtbuf,
    unsigned short* __restrict__ obuf)
{
    // smem reused across phases (barrier-sequenced):
    //   loop phase : per-wave P tiles [4][32][40] shorts (10,240 B)
    //   merge phase: accS [4][32][68] f32 (34,816 B) + mS[4][32] + lS[4][32]
    __shared__ char smem[4 * 32 * 68 * 4 + 512 + 512] __attribute__((aligned(16)));
    unsigned short (*Ps)[32][40] = (unsigned short (*)[32][40])smem;
    float* accS = (float*)smem;                       // [4][32][68]
    float* mS = (float*)(smem + 4 * 32 * 68 * 4);     // [4][32]
    float* lS = mS + 128;                              // [4][32]

    int bh = blockIdx.y, j = blockIdx.x;
    const unsigned short* Q  = qbuf + (long)bh * 65536;
    const unsigned short* Kp = kbuf + (long)bh * 65536;
    const unsigned short* VT = vtbuf + (long)bh * 65536;   // [64 d][1024 n]
    unsigned short* O = obuf + (long)bh * 65536;
    int t = threadIdx.x, lane = t & 63, w = t >> 6;
    int lrow = lane >> 4, lcol = lane & 15;
    const float NEG = -__builtin_inff();

    #pragma unroll
    for (int pass = 0; pass < 2; ++pass) {
        int qt = pass == 0 ? j : 31 - j;
        int qbase = qt * 32;
        int T = qt + 1;                                // number of 32-key tiles

        // Q B-fragments: Q[q = qbase+qg*16+lcol][d = kc*32+lrow*8+jj]
        bf16x8 qf[2][2];
        #pragma unroll
        for (int qg = 0; qg < 2; ++qg)
            #pragma unroll
            for (int kc = 0; kc < 2; ++kc)
                qf[qg][kc] = ld_frag(Q + (long)(qbase + qg * 16 + lcol) * 64 + kc * 32 + lrow * 8);

        f32x4 acc[2][4] = {};
        float m_i[2] = {NEG, NEG}, l_i[2] = {0.f, 0.f};

        if (w < T) {
            int kt = w * 32;
            bf16x8 kf[2][2];
            #pragma unroll
            for (int kg = 0; kg < 2; ++kg)
                #pragma unroll
                for (int kc = 0; kc < 2; ++kc)
                    kf[kg][kc] = ld_frag(Kp + (long)(kt + kg * 16 + lcol) * 64 + kc * 32 + lrow * 8);

            for (;; kt += 128) {
                // --- S^T = K * Q ---
                f32x4 s[2][2] = {};
                __builtin_amdgcn_s_setprio(1);
                #pragma unroll
                for (int kg = 0; kg < 2; ++kg)
                    #pragma unroll
                    for (int kc = 0; kc < 2; ++kc) {
                        s[0][kg] = __builtin_amdgcn_mfma_f32_16x16x32_bf16(kf[kg][kc], qf[0][kc], s[0][kg], 0, 0, 0);
                        s[1][kg] = __builtin_amdgcn_mfma_f32_16x16x32_bf16(kf[kg][kc], qf[1][kc], s[1][kg], 0, 0, 0);
                    }
                __builtin_amdgcn_s_setprio(0);

                bool more = kt + 128 < T * 32;
                bf16x8 kn[2][2];
                if (more) {
                    #pragma unroll
                    for (int kg = 0; kg < 2; ++kg)
                        #pragma unroll
                        for (int kc = 0; kc < 2; ++kc)
                            kn[kg][kc] = ld_frag(Kp + (long)(kt + 128 + kg * 16 + lcol) * 64 + kc * 32 + lrow * 8);
                }
                bf16x8 vf[4];
                #pragma unroll
                for (int dg = 0; dg < 4; ++dg)
                    vf[dg] = ld_frag(VT + (long)(dg * 16 + lcol) * 1024 + kt + lrow * 8);

                // --- lane-local online softmax (q = qbase+qg*16+lcol) ---
                #pragma unroll
                for (int qg = 0; qg < 2; ++qg) {
                    int q = qbase + qg * 16 + lcol;
                    float tv[8];
                    float mx = NEG;
                    #pragma unroll
                    for (int kg = 0; kg < 2; ++kg)
                        #pragma unroll
                        for (int r = 0; r < 4; ++r) {
                            int kglob = kt + kg * 16 + lrow * 4 + r;
                            float v = s[qg][kg][r] * 0.125f;
                            tv[kg * 4 + r] = kglob > q ? NEG : v;
                            mx = fmaxf(mx, tv[kg * 4 + r]);
                        }
                    mx = fmaxf(mx, __shfl_xor(mx, 16));
                    mx = fmaxf(mx, __shfl_xor(mx, 32));
                    float mnew = fmaxf(m_i[qg], mx);
                    float alpha = __expf(m_i[qg] - mnew);
                    float p[8], ps = 0.f;
                    #pragma unroll
                    for (int jj = 0; jj < 8; ++jj) { p[jj] = __expf(tv[jj] - mnew); ps += p[jj]; }
                    #pragma unroll
                    for (int kg = 0; kg < 2; ++kg) {
                        ushort4 pk;
                        pk.x = f2bf(p[kg * 4 + 0]); pk.y = f2bf(p[kg * 4 + 1]);
                        pk.z = f2bf(p[kg * 4 + 2]); pk.w = f2bf(p[kg * 4 + 3]);
                        *(ushort4*)&Ps[w][qg * 16 + lcol][kg * 16 + lrow * 4] = pk;
                    }
                    ps += __shfl_xor(ps, 16);
                    ps += __shfl_xor(ps, 32);
                    l_i[qg] = l_i[qg] * alpha + ps;
                    m_i[qg] = mnew;
                    #pragma unroll
                    for (int dg = 0; dg < 4; ++dg)
                        #pragma unroll
                        for (int r = 0; r < 4; ++r)
                            acc[qg][dg][r] *= alpha;
                }

                // --- O^T += V^T * P ---
                bf16x8 pb[2];
                pb[0] = ld_frag(&Ps[w][lcol][lrow * 8]);
                pb[1] = ld_frag(&Ps[w][16 + lcol][lrow * 8]);
                __builtin_amdgcn_s_setprio(1);
                #pragma unroll
                for (int dg = 0; dg < 4; ++dg) {
                    acc[0][dg] = __builtin_amdgcn_mfma_f32_16x16x32_bf16(vf[dg], pb[0], acc[0][dg], 0, 0, 0);
                    acc[1][dg] = __builtin_amdgcn_mfma_f32_16x16x32_bf16(vf[dg], pb[1], acc[1][dg], 0, 0, 0);
                }
                __builtin_amdgcn_s_setprio(0);

                if (!more) break;
                #pragma unroll
                for (int kg = 0; kg < 2; ++kg)
                    #pragma unroll
                    for (int kc = 0; kc < 2; ++kc)
                        kf[kg][kc] = kn[kg][kc];
            }
        }

        // --- merge 4 wave-partials through LDS ---
        __syncthreads();   // all Ps usage (this pass) and prior-pass merge reads done
        #pragma unroll
        for (int qg = 0; qg < 2; ++qg) {
            int q = qg * 16 + lcol;
            if (lrow == 0) { mS[w * 32 + q] = m_i[qg]; lS[w * 32 + q] = l_i[qg]; }
            #pragma unroll
            for (int dg = 0; dg < 4; ++dg)
                *(f32x4*)&accS[(w * 32 + q) * 68 + dg * 16 + lrow * 4] = acc[qg][dg];
        }
        __syncthreads();

        {
            int qq = t >> 3, d0 = (t & 7) * 8;
            float m0 = mS[qq], m1 = mS[32 + qq], m2 = mS[64 + qq], m3 = mS[96 + qq];
            float M = fmaxf(fmaxf(m0, m1), fmaxf(m2, m3));
            float e0 = __expf(m0 - M), e1 = __expf(m1 - M), e2 = __expf(m2 - M), e3 = __expf(m3 - M);
            float L = e0 * lS[qq] + e1 * lS[32 + qq] + e2 * lS[64 + qq] + e3 * lS[96 + qq];
            float inv = 1.f / L;
            const float* a0 = &accS[qq * 68 + d0];
            const float* a1 = &accS[(32 + qq) * 68 + d0];
            const float* a2 = &accS[(64 + qq) * 68 + d0];
            const float* a3 = &accS[(96 + qq) * 68 + d0];
            unsigned short h[8];
            #pragma unroll
            for (int jj = 0; jj < 8; ++jj)
                h[jj] = f2bf((e0 * a0[jj] + e1 * a1[jj] + e2 * a2[jj] + e3 * a3[jj]) * inv);
            uint4 pk;
            pk.x = (unsigned)h[0] | ((unsigned)h[1] << 16);
            pk.y = (unsigned)h[2] | ((unsigned)h[3] << 16);
            pk.z = (unsigned)h[4] | ((unsigned)h[5] << 16);
            pk.w = (unsigned)h[6] | ((unsigned)h[7] << 16);
            *(uint4*)&O[(long)(qbase + qq) * 64 + d0] = pk;
        }
        __syncthreads();   // merge reads done before next pass overwrites smem
    }
}

extern "C" void kernel_launch(void* const* d_in, const int* in_sizes, int n_in,
                              void* d_out, int out_size, void* d_ws, size_t ws_size,
                              hipStream_t stream) {
    const float* x    = (const float*)d_in[0];
    const float* Wqkv = (const float*)d_in[1];
    const float* bqkv = (const float*)d_in[2];
    const float* Wfc  = (const float*)d_in[3];
    const float* bfc  = (const float*)d_in[4];
    float* out = (float*)d_out;

    unsigned short* ws    = (unsigned short*)d_ws;
    unsigned short* xb    = ws;                    // 4M elems; dead after gemm<0>
    unsigned short* wqkvT = xb + (4u << 20);       // 3M
    unsigned short* wfcT  = wqkvT + (3u << 20);    // 1M
    unsigned short* qb    = wfcT + (1u << 20);     // 4M
    unsigned short* kb    = qb + (4u << 20);       // 4M
    unsigned short* vbT   = kb + (4u << 20);       // 4M
    unsigned short* ob    = xb;                    // reuse xb
    // total ws: 40 MB

    cvt_bf16<<<dim3(2048), dim3(256), 0, stream>>>(x, xb, (4 << 20) / 4);
    transpose_cvt<<<dim3(3072 / 32, 1024 / 32), dim3(32, 8), 0, stream>>>(Wqkv, wqkvT, 1024, 3072);
    transpose_cvt<<<dim3(1024 / 32, 1024 / 32), dim3(32, 8), 0, stream>>>(Wfc, wfcT, 1024, 1024);

    gemm128<0><<<dim3(24, 32), dim3(256), 0, stream>>>(xb, wqkvT, bqkv, qb, kb, vbT, nullptr);
    attn<<<dim3(16, 64), dim3(256), 0, stream>>>(qb, kb, vbT, ob);
    gemm128<1><<<dim3(8, 32), dim3(256), 0, stream>>>(ob, wfcT, bfc, nullptr, nullptr, nullptr, out);
}

// Round 7
// 121.286 us; speedup vs baseline: 1.6890x; 1.1090x over previous
//
#include <hip/hip_runtime.h>

// B=4, N=1024, E=1024, H=16, D=64.  bf16 MFMA (16x16x32), fp32 accum.
// Raw-reshape: per batch-head bh, Q/K/V slab = flat [bh*65536, +65536) viewed [1024 n][64 d].
// QKV GEMM writes q/k/v linearly (coalesced); a separate LDS-tiled transpose_v builds
// V^T per head ([64 d][1024 n]) so attention PV B-fragments are contiguous 16B loads.
// (Round-6 lesson: fusing V^T into the GEMM epilogue scatters 2B stores -> 8x write
// amplification, 95.7 MB written vs 25 MB ideal.)
// Attention: swapped QK^T (S^T=K*Q, lane-local softmax), 4-wave split-K with LDS merge,
// causal pairing (block j owns q-tiles {j, 31-j} -> uniform 33 key-tiles/block).

typedef __bf16 bf16x8 __attribute__((ext_vector_type(8)));
typedef float f32x4 __attribute__((ext_vector_type(4)));

__device__ __forceinline__ unsigned short f2bf(float f) {
    unsigned u = __float_as_uint(f);
    u += 0x7fffu + ((u >> 16) & 1u);   // round-to-nearest-even
    return (unsigned short)(u >> 16);
}

union FragU { uint4 u; bf16x8 v; };

__device__ __forceinline__ bf16x8 ld_frag(const unsigned short* p) {
    FragU x; x.u = *(const uint4*)p; return x.v;
}

__device__ __forceinline__ void gload_lds16(const void* g, void* l) {
    __builtin_amdgcn_global_load_lds(
        (const __attribute__((address_space(1))) void*)g,
        (__attribute__((address_space(3))) void*)l, 16, 0, 0);
}

// ---------------- fp32 -> bf16 elementwise ----------------
__global__ void cvt_bf16(const float* __restrict__ in, unsigned short* __restrict__ out, int n4) {
    int i = blockIdx.x * blockDim.x + threadIdx.x;
    int stride = gridDim.x * blockDim.x;
    for (; i < n4; i += stride) {
        float4 f = ((const float4*)in)[i];
        unsigned a = (unsigned)f2bf(f.x) | ((unsigned)f2bf(f.y) << 16);
        unsigned b = (unsigned)f2bf(f.z) | ((unsigned)f2bf(f.w) << 16);
        ((uint2*)out)[i] = make_uint2(a, b);
    }
}

// ---------------- fp32 [rows][cols] -> bf16 [cols][rows] ----------------
__global__ void transpose_cvt(const float* __restrict__ W, unsigned short* __restrict__ Wt,
                              int rows, int cols) {
    __shared__ float tile[32][33];
    int c0 = blockIdx.x * 32, r0 = blockIdx.y * 32;
    for (int i = threadIdx.y; i < 32; i += 8)
        tile[i][threadIdx.x] = W[(r0 + i) * cols + c0 + threadIdx.x];
    __syncthreads();
    for (int i = threadIdx.y; i < 32; i += 8)
        Wt[(c0 + i) * (long)rows + r0 + threadIdx.x] = f2bf(tile[threadIdx.x][i]);
}

// ---------------- per-head V transpose: [1024 n][64 d] -> [64 d][1024 n] ----------------
__global__ void transpose_v(const unsigned short* __restrict__ v,
                            unsigned short* __restrict__ vt) {
    __shared__ unsigned short tile[32][33];
    int bh = blockIdx.z;
    int n0 = blockIdx.x * 32, d0 = blockIdx.y * 32;
    const unsigned short* src = v + (long)bh * 65536;
    unsigned short* dst = vt + (long)bh * 65536;
    for (int i = threadIdx.y; i < 32; i += 8)
        tile[i][threadIdx.x] = src[(n0 + i) * 64 + d0 + threadIdx.x];
    __syncthreads();
    for (int i = threadIdx.y; i < 32; i += 8)
        dst[(d0 + i) * 1024 + n0 + threadIdx.x] = tile[threadIdx.x][i];
}

// ---------------- bf16 GEMM, 128x128 tile, double-buffered global_load_lds ----------------
// MODE 0: N=3072 -> q/k/v row-major flat (all coalesced).  MODE 1: N=1024 -> fp32 out.
template <int MODE>
__global__ __launch_bounds__(256) void gemm128(
    const unsigned short* __restrict__ A,    // [M,1024] bf16
    const unsigned short* __restrict__ Bt,   // [N,1024] bf16
    const float* __restrict__ bias,          // [N]
    unsigned short* __restrict__ qb,
    unsigned short* __restrict__ kb,
    unsigned short* __restrict__ vb,
    float* __restrict__ outf)
{
    const int K = 1024;
    __shared__ unsigned short As[2][4096];   // [128][32] linear per buffer
    __shared__ unsigned short Bs[2][4096];
    int t = threadIdx.x, lane = t & 63, w = t >> 6;
    int wm = w >> 1, wn = w & 1;             // 2x2 waves, 64x64 per wave
    int lrow = lane >> 4, lcol = lane & 15;
    int tn0 = blockIdx.x * 128, tm0 = blockIdx.y * 128;

    int seg0 = w * 1024;
    int seg1 = (w + 4) * 1024;
    int off0 = seg0 + lane * 16, off1 = seg1 + lane * 16;
    int r0 = off0 >> 6, cb0 = off0 & 63;
    int r1 = off1 >> 6, cb1 = off1 & 63;

    const char* gA = (const char*)A;
    const char* gB = (const char*)Bt;

    f32x4 acc[4][4] = {};

    auto STAGE = [&](int buf, int kt) {
        long kby = (long)kt * 2;
        gload_lds16(gA + (long)(tm0 + r0) * 2048 + kby + cb0, (char*)&As[buf][0] + seg0);
        gload_lds16(gA + (long)(tm0 + r1) * 2048 + kby + cb1, (char*)&As[buf][0] + seg1);
        gload_lds16(gB + (long)(tn0 + r0) * 2048 + kby + cb0, (char*)&Bs[buf][0] + seg0);
        gload_lds16(gB + (long)(tn0 + r1) * 2048 + kby + cb1, (char*)&Bs[buf][0] + seg1);
    };

    STAGE(0, 0);
    asm volatile("s_waitcnt vmcnt(0)");
    __syncthreads();

    int cur = 0;
    for (int kt = 0; kt < K; kt += 32) {
        if (kt + 32 < K) STAGE(cur ^ 1, kt + 32);

        bf16x8 af[4], bfr[4];
        #pragma unroll
        for (int mi = 0; mi < 4; ++mi)
            af[mi] = ld_frag(&As[cur][0] + (wm * 64 + mi * 16 + lcol) * 32 + lrow * 8);
        #pragma unroll
        for (int ni = 0; ni < 4; ++ni)
            bfr[ni] = ld_frag(&Bs[cur][0] + (wn * 64 + ni * 16 + lcol) * 32 + lrow * 8);
        #pragma unroll
        for (int mi = 0; mi < 4; ++mi)
            #pragma unroll
            for (int ni = 0; ni < 4; ++ni)
                acc[mi][ni] = __builtin_amdgcn_mfma_f32_16x16x32_bf16(af[mi], bfr[ni], acc[mi][ni], 0, 0, 0);

        __syncthreads();
        cur ^= 1;
    }

    #pragma unroll
    for (int mi = 0; mi < 4; ++mi) {
        int gr0 = tm0 + wm * 64 + mi * 16 + lrow * 4;
        #pragma unroll
        for (int ni = 0; ni < 4; ++ni) {
            int gc = tn0 + wn * 64 + ni * 16 + lcol;
            float bv = bias[gc];
            if (MODE == 0) {
                int sec = gc >> 10, ei = gc & 1023;
                unsigned short* dst = sec == 0 ? qb : (sec == 1 ? kb : vb);
                #pragma unroll
                for (int r = 0; r < 4; ++r)
                    dst[(long)(gr0 + r) * 1024 + ei] = f2bf(acc[mi][ni][r] + bv);
            } else {
                #pragma unroll
                for (int r = 0; r < 4; ++r)
                    outf[(long)(gr0 + r) * 1024 + gc] = acc[mi][ni][r] + bv;
            }
        }
    }
}

// ---------------- flash attention: swapped QK^T + 4-wave split-K + causal pairing ----------------
__global__ __launch_bounds__(256) void attn(
    const unsigned short* __restrict__ qbuf,
    const unsigned short* __restrict__ kbuf,
    const unsigned short* __restrict__ vtbuf,
    unsigned short* __restrict__ obuf)
{
    // smem reused across phases (barrier-sequenced):
    //   loop phase : per-wave P tiles [4][32][40] shorts (10,240 B)
    //   merge phase: accS [4][32][68] f32 (34,816 B) + mS[4][32] + lS[4][32]
    __shared__ char smem[4 * 32 * 68 * 4 + 512 + 512] __attribute__((aligned(16)));
    unsigned short (*Ps)[32][40] = (unsigned short (*)[32][40])smem;
    float* accS = (float*)smem;                       // [4][32][68]
    float* mS = (float*)(smem + 4 * 32 * 68 * 4);     // [4][32]
    float* lS = mS + 128;                              // [4][32]

    int bh = blockIdx.y, j = blockIdx.x;
    const unsigned short* Q  = qbuf + (long)bh * 65536;
    const unsigned short* Kp = kbuf + (long)bh * 65536;
    const unsigned short* VT = vtbuf + (long)bh * 65536;   // [64 d][1024 n]
    unsigned short* O = obuf + (long)bh * 65536;
    int t = threadIdx.x, lane = t & 63, w = t >> 6;
    int lrow = lane >> 4, lcol = lane & 15;
    const float NEG = -__builtin_inff();

    #pragma unroll
    for (int pass = 0; pass < 2; ++pass) {
        int qt = pass == 0 ? j : 31 - j;
        int qbase = qt * 32;
        int T = qt + 1;                                // number of 32-key tiles

        bf16x8 qf[2][2];
        #pragma unroll
        for (int qg = 0; qg < 2; ++qg)
            #pragma unroll
            for (int kc = 0; kc < 2; ++kc)
                qf[qg][kc] = ld_frag(Q + (long)(qbase + qg * 16 + lcol) * 64 + kc * 32 + lrow * 8);

        f32x4 acc[2][4] = {};
        float m_i[2] = {NEG, NEG}, l_i[2] = {0.f, 0.f};

        if (w < T) {
            int kt = w * 32;
            bf16x8 kf[2][2];
            #pragma unroll
            for (int kg = 0; kg < 2; ++kg)
                #pragma unroll
                for (int kc = 0; kc < 2; ++kc)
                    kf[kg][kc] = ld_frag(Kp + (long)(kt + kg * 16 + lcol) * 64 + kc * 32 + lrow * 8);

            for (;; kt += 128) {
                // --- S^T = K * Q ---
                f32x4 s[2][2] = {};
                __builtin_amdgcn_s_setprio(1);
                #pragma unroll
                for (int kg = 0; kg < 2; ++kg)
                    #pragma unroll
                    for (int kc = 0; kc < 2; ++kc) {
                        s[0][kg] = __builtin_amdgcn_mfma_f32_16x16x32_bf16(kf[kg][kc], qf[0][kc], s[0][kg], 0, 0, 0);
                        s[1][kg] = __builtin_amdgcn_mfma_f32_16x16x32_bf16(kf[kg][kc], qf[1][kc], s[1][kg], 0, 0, 0);
                    }
                __builtin_amdgcn_s_setprio(0);

                bool more = kt + 128 < T * 32;
                bf16x8 kn[2][2];
                if (more) {
                    #pragma unroll
                    for (int kg = 0; kg < 2; ++kg)
                        #pragma unroll
                        for (int kc = 0; kc < 2; ++kc)
                            kn[kg][kc] = ld_frag(Kp + (long)(kt + 128 + kg * 16 + lcol) * 64 + kc * 32 + lrow * 8);
                }
                bf16x8 vf[4];
                #pragma unroll
                for (int dg = 0; dg < 4; ++dg)
                    vf[dg] = ld_frag(VT + (long)(dg * 16 + lcol) * 1024 + kt + lrow * 8);

                // --- lane-local online softmax (q = qbase+qg*16+lcol) ---
                #pragma unroll
                for (int qg = 0; qg < 2; ++qg) {
                    int q = qbase + qg * 16 + lcol;
                    float tv[8];
                    float mx = NEG;
                    #pragma unroll
                    for (int kg = 0; kg < 2; ++kg)
                        #pragma unroll
                        for (int r = 0; r < 4; ++r) {
                            int kglob = kt + kg * 16 + lrow * 4 + r;
                            float v = s[qg][kg][r] * 0.125f;
                            tv[kg * 4 + r] = kglob > q ? NEG : v;
                            mx = fmaxf(mx, tv[kg * 4 + r]);
                        }
                    mx = fmaxf(mx, __shfl_xor(mx, 16));
                    mx = fmaxf(mx, __shfl_xor(mx, 32));
                    float mnew = fmaxf(m_i[qg], mx);
                    float alpha = __expf(m_i[qg] - mnew);
                    float p[8], ps = 0.f;
                    #pragma unroll
                    for (int jj = 0; jj < 8; ++jj) { p[jj] = __expf(tv[jj] - mnew); ps += p[jj]; }
                    #pragma unroll
                    for (int kg = 0; kg < 2; ++kg) {
                        ushort4 pk;
                        pk.x = f2bf(p[kg * 4 + 0]); pk.y = f2bf(p[kg * 4 + 1]);
                        pk.z = f2bf(p[kg * 4 + 2]); pk.w = f2bf(p[kg * 4 + 3]);
                        *(ushort4*)&Ps[w][qg * 16 + lcol][kg * 16 + lrow * 4] = pk;
                    }
                    ps += __shfl_xor(ps, 16);
                    ps += __shfl_xor(ps, 32);
                    l_i[qg] = l_i[qg] * alpha + ps;
                    m_i[qg] = mnew;
                    #pragma unroll
                    for (int dg = 0; dg < 4; ++dg)
                        #pragma unroll
                        for (int r = 0; r < 4; ++r)
                            acc[qg][dg][r] *= alpha;
                }

                // --- O^T += V^T * P ---
                bf16x8 pb[2];
                pb[0] = ld_frag(&Ps[w][lcol][lrow * 8]);
                pb[1] = ld_frag(&Ps[w][16 + lcol][lrow * 8]);
                __builtin_amdgcn_s_setprio(1);
                #pragma unroll
                for (int dg = 0; dg < 4; ++dg) {
                    acc[0][dg] = __builtin_amdgcn_mfma_f32_16x16x32_bf16(vf[dg], pb[0], acc[0][dg], 0, 0, 0);
                    acc[1][dg] = __builtin_amdgcn_mfma_f32_16x16x32_bf16(vf[dg], pb[1], acc[1][dg], 0, 0, 0);
                }
                __builtin_amdgcn_s_setprio(0);

                if (!more) break;
                #pragma unroll
                for (int kg = 0; kg < 2; ++kg)
                    #pragma unroll
                    for (int kc = 0; kc < 2; ++kc)
                        kf[kg][kc] = kn[kg][kc];
            }
        }

        // --- merge 4 wave-partials through LDS ---
        __syncthreads();
        #pragma unroll
        for (int qg = 0; qg < 2; ++qg) {
            int q = qg * 16 + lcol;
            if (lrow == 0) { mS[w * 32 + q] = m_i[qg]; lS[w * 32 + q] = l_i[qg]; }
            #pragma unroll
            for (int dg = 0; dg < 4; ++dg)
                *(f32x4*)&accS[(w * 32 + q) * 68 + dg * 16 + lrow * 4] = acc[qg][dg];
        }
        __syncthreads();

        {
            int qq = t >> 3, d0 = (t & 7) * 8;
            float m0 = mS[qq], m1 = mS[32 + qq], m2 = mS[64 + qq], m3 = mS[96 + qq];
            float M = fmaxf(fmaxf(m0, m1), fmaxf(m2, m3));
            float e0 = __expf(m0 - M), e1 = __expf(m1 - M), e2 = __expf(m2 - M), e3 = __expf(m3 - M);
            float L = e0 * lS[qq] + e1 * lS[32 + qq] + e2 * lS[64 + qq] + e3 * lS[96 + qq];
            float inv = 1.f / L;
            const float* a0 = &accS[qq * 68 + d0];
            const float* a1 = &accS[(32 + qq) * 68 + d0];
            const float* a2 = &accS[(64 + qq) * 68 + d0];
            const float* a3 = &accS[(96 + qq) * 68 + d0];
            unsigned short h[8];
            #pragma unroll
            for (int jj = 0; jj < 8; ++jj)
                h[jj] = f2bf((e0 * a0[jj] + e1 * a1[jj] + e2 * a2[jj] + e3 * a3[jj]) * inv);
            uint4 pk;
            pk.x = (unsigned)h[0] | ((unsigned)h[1] << 16);
            pk.y = (unsigned)h[2] | ((unsigned)h[3] << 16);
            pk.z = (unsigned)h[4] | ((unsigned)h[5] << 16);
            pk.w = (unsigned)h[6] | ((unsigned)h[7] << 16);
            *(uint4*)&O[(long)(qbase + qq) * 64 + d0] = pk;
        }
        __syncthreads();
    }
}

extern "C" void kernel_launch(void* const* d_in, const int* in_sizes, int n_in,
                              void* d_out, int out_size, void* d_ws, size_t ws_size,
                              hipStream_t stream) {
    const float* x    = (const float*)d_in[0];
    const float* Wqkv = (const float*)d_in[1];
    const float* bqkv = (const float*)d_in[2];
    const float* Wfc  = (const float*)d_in[3];
    const float* bfc  = (const float*)d_in[4];
    float* out = (float*)d_out;

    unsigned short* ws    = (unsigned short*)d_ws;
    unsigned short* xb    = ws;                    // 4M elems; dead after gemm<0>
    unsigned short* wqkvT = xb + (4u << 20);       // 3M
    unsigned short* wfcT  = wqkvT + (3u << 20);    // 1M
    unsigned short* qb    = wfcT + (1u << 20);     // 4M
    unsigned short* kb    = qb + (4u << 20);       // 4M
    unsigned short* vb    = kb + (4u << 20);       // 4M; dead after transpose_v
    unsigned short* vbT   = xb;                    // reuse xb
    unsigned short* ob    = vb;                    // reuse vb
    // total ws: 40 MB

    cvt_bf16<<<dim3(2048), dim3(256), 0, stream>>>(x, xb, (4 << 20) / 4);
    transpose_cvt<<<dim3(3072 / 32, 1024 / 32), dim3(32, 8), 0, stream>>>(Wqkv, wqkvT, 1024, 3072);
    transpose_cvt<<<dim3(1024 / 32, 1024 / 32), dim3(32, 8), 0, stream>>>(Wfc, wfcT, 1024, 1024);

    gemm128<0><<<dim3(24, 32), dim3(256), 0, stream>>>(xb, wqkvT, bqkv, qb, kb, vb, nullptr);
    transpose_v<<<dim3(32, 2, 64), dim3(32, 8), 0, stream>>>(vb, vbT);
    attn<<<dim3(16, 64), dim3(256), 0, stream>>>(qb, kb, vbT, ob);
    gemm128<1><<<dim3(8, 32), dim3(256), 0, stream>>>(ob, wfcT, bfc, nullptr, nullptr, nullptr, out);
}

// Round 8
// 120.914 us; speedup vs baseline: 1.6942x; 1.0031x over previous
//
#include <hip/hip_runtime.h>

// B=4, N=1024, E=1024, H=16, D=64.  bf16 MFMA (16x16x32), fp32 accum.
// Raw-reshape: per batch-head bh, Q/K/V slab = flat [bh*65536, +65536) viewed [1024 n][64 d].
// QKV GEMM writes q/k/v linearly (coalesced); transpose_v builds V^T per head
// ([64 d][1024 n]) so attention PV B-fragments are contiguous 16B loads.
// Attention: swapped QK^T (S^T=K*Q, lane-local softmax), 4-wave split-K with LDS merge,
// causal pairing (block j owns q-tiles {j, 31-j}), XCD-aware remap (all 16 j-blocks of a
// bh land on XCD bh&7 -> slab L2-resident), defer-max rescale (T13, THR=8).

typedef __bf16 bf16x8 __attribute__((ext_vector_type(8)));
typedef float f32x4 __attribute__((ext_vector_type(4)));

__device__ __forceinline__ unsigned short f2bf(float f) {
    unsigned u = __float_as_uint(f);
    u += 0x7fffu + ((u >> 16) & 1u);   // round-to-nearest-even
    return (unsigned short)(u >> 16);
}

union FragU { uint4 u; bf16x8 v; };

__device__ __forceinline__ bf16x8 ld_frag(const unsigned short* p) {
    FragU x; x.u = *(const uint4*)p; return x.v;
}

__device__ __forceinline__ void gload_lds16(const void* g, void* l) {
    __builtin_amdgcn_global_load_lds(
        (const __attribute__((address_space(1))) void*)g,
        (__attribute__((address_space(3))) void*)l, 16, 0, 0);
}

// ---------------- fp32 -> bf16 elementwise ----------------
__global__ void cvt_bf16(const float* __restrict__ in, unsigned short* __restrict__ out, int n4) {
    int i = blockIdx.x * blockDim.x + threadIdx.x;
    int stride = gridDim.x * blockDim.x;
    for (; i < n4; i += stride) {
        float4 f = ((const float4*)in)[i];
        unsigned a = (unsigned)f2bf(f.x) | ((unsigned)f2bf(f.y) << 16);
        unsigned b = (unsigned)f2bf(f.z) | ((unsigned)f2bf(f.w) << 16);
        ((uint2*)out)[i] = make_uint2(a, b);
    }
}

// ---------------- fp32 [rows][cols] -> bf16 [cols][rows] ----------------
__global__ void transpose_cvt(const float* __restrict__ W, unsigned short* __restrict__ Wt,
                              int rows, int cols) {
    __shared__ float tile[32][33];
    int c0 = blockIdx.x * 32, r0 = blockIdx.y * 32;
    for (int i = threadIdx.y; i < 32; i += 8)
        tile[i][threadIdx.x] = W[(r0 + i) * cols + c0 + threadIdx.x];
    __syncthreads();
    for (int i = threadIdx.y; i < 32; i += 8)
        Wt[(c0 + i) * (long)rows + r0 + threadIdx.x] = f2bf(tile[threadIdx.x][i]);
}

// ---------------- per-head V transpose: [1024 n][64 d] -> [64 d][1024 n] ----------------
__global__ void transpose_v(const unsigned short* __restrict__ v,
                            unsigned short* __restrict__ vt) {
    __shared__ unsigned short tile[32][33];
    int bh = blockIdx.z;
    int n0 = blockIdx.x * 32, d0 = blockIdx.y * 32;
    const unsigned short* src = v + (long)bh * 65536;
    unsigned short* dst = vt + (long)bh * 65536;
    for (int i = threadIdx.y; i < 32; i += 8)
        tile[i][threadIdx.x] = src[(n0 + i) * 64 + d0 + threadIdx.x];
    __syncthreads();
    for (int i = threadIdx.y; i < 32; i += 8)
        dst[(d0 + i) * 1024 + n0 + threadIdx.x] = tile[threadIdx.x][i];
}

// ---------------- bf16 GEMM, 128x128 tile, double-buffered global_load_lds ----------------
template <int MODE>
__global__ __launch_bounds__(256) void gemm128(
    const unsigned short* __restrict__ A,    // [M,1024] bf16
    const unsigned short* __restrict__ Bt,   // [N,1024] bf16
    const float* __restrict__ bias,          // [N]
    unsigned short* __restrict__ qb,
    unsigned short* __restrict__ kb,
    unsigned short* __restrict__ vb,
    float* __restrict__ outf)
{
    const int K = 1024;
    __shared__ unsigned short As[2][4096];   // [128][32] linear per buffer
    __shared__ unsigned short Bs[2][4096];
    int t = threadIdx.x, lane = t & 63, w = t >> 6;
    int wm = w >> 1, wn = w & 1;             // 2x2 waves, 64x64 per wave
    int lrow = lane >> 4, lcol = lane & 15;
    int tn0 = blockIdx.x * 128, tm0 = blockIdx.y * 128;

    int seg0 = w * 1024;
    int seg1 = (w + 4) * 1024;
    int off0 = seg0 + lane * 16, off1 = seg1 + lane * 16;
    int r0 = off0 >> 6, cb0 = off0 & 63;
    int r1 = off1 >> 6, cb1 = off1 & 63;

    const char* gA = (const char*)A;
    const char* gB = (const char*)Bt;

    f32x4 acc[4][4] = {};

    auto STAGE = [&](int buf, int kt) {
        long kby = (long)kt * 2;
        gload_lds16(gA + (long)(tm0 + r0) * 2048 + kby + cb0, (char*)&As[buf][0] + seg0);
        gload_lds16(gA + (long)(tm0 + r1) * 2048 + kby + cb1, (char*)&As[buf][0] + seg1);
        gload_lds16(gB + (long)(tn0 + r0) * 2048 + kby + cb0, (char*)&Bs[buf][0] + seg0);
        gload_lds16(gB + (long)(tn0 + r1) * 2048 + kby + cb1, (char*)&Bs[buf][0] + seg1);
    };

    STAGE(0, 0);
    asm volatile("s_waitcnt vmcnt(0)");
    __syncthreads();

    int cur = 0;
    for (int kt = 0; kt < K; kt += 32) {
        if (kt + 32 < K) STAGE(cur ^ 1, kt + 32);

        bf16x8 af[4], bfr[4];
        #pragma unroll
        for (int mi = 0; mi < 4; ++mi)
            af[mi] = ld_frag(&As[cur][0] + (wm * 64 + mi * 16 + lcol) * 32 + lrow * 8);
        #pragma unroll
        for (int ni = 0; ni < 4; ++ni)
            bfr[ni] = ld_frag(&Bs[cur][0] + (wn * 64 + ni * 16 + lcol) * 32 + lrow * 8);
        #pragma unroll
        for (int mi = 0; mi < 4; ++mi)
            #pragma unroll
            for (int ni = 0; ni < 4; ++ni)
                acc[mi][ni] = __builtin_amdgcn_mfma_f32_16x16x32_bf16(af[mi], bfr[ni], acc[mi][ni], 0, 0, 0);

        __syncthreads();
        cur ^= 1;
    }

    #pragma unroll
    for (int mi = 0; mi < 4; ++mi) {
        int gr0 = tm0 + wm * 64 + mi * 16 + lrow * 4;
        #pragma unroll
        for (int ni = 0; ni < 4; ++ni) {
            int gc = tn0 + wn * 64 + ni * 16 + lcol;
            float bv = bias[gc];
            if (MODE == 0) {
                int sec = gc >> 10, ei = gc & 1023;
                unsigned short* dst = sec == 0 ? qb : (sec == 1 ? kb : vb);
                #pragma unroll
                for (int r = 0; r < 4; ++r)
                    dst[(long)(gr0 + r) * 1024 + ei] = f2bf(acc[mi][ni][r] + bv);
            } else {
                #pragma unroll
                for (int r = 0; r < 4; ++r)
                    outf[(long)(gr0 + r) * 1024 + gc] = acc[mi][ni][r] + bv;
            }
        }
    }
}

// ---------------- flash attention: swapped QK^T + split-K + pairing + XCD remap ----------------
__global__ __launch_bounds__(256) void attn(
    const unsigned short* __restrict__ qbuf,
    const unsigned short* __restrict__ kbuf,
    const unsigned short* __restrict__ vtbuf,
    unsigned short* __restrict__ obuf)
{
    // smem reused across phases (barrier-sequenced):
    //   loop phase : per-wave P tiles [4][32][40] shorts (10,240 B)
    //   merge phase: accS [4][32][68] f32 (34,816 B) + mS[4][32] + lS[4][32]
    __shared__ char smem[4 * 32 * 68 * 4 + 512 + 512] __attribute__((aligned(16)));
    unsigned short (*Ps)[32][40] = (unsigned short (*)[32][40])smem;
    float* accS = (float*)smem;                       // [4][32][68]
    float* mS = (float*)(smem + 4 * 32 * 68 * 4);     // [4][32]
    float* lS = mS + 128;                              // [4][32]

    // XCD remap: hardware round-robins linear blockIdx across 8 XCDs (id%8 = XCD).
    // Assign bh = xcd + 8*(slot>>4) so all 16 j-blocks of a bh run on one XCD ->
    // its 384KB slab stays L2-resident (8 slabs = 3MB < 4MB L2/XCD).
    int id = blockIdx.x;
    int xcd = id & 7, slot = id >> 3;
    int bh = xcd + 8 * (slot >> 4);
    int j = slot & 15;

    const unsigned short* Q  = qbuf + (long)bh * 65536;
    const unsigned short* Kp = kbuf + (long)bh * 65536;
    const unsigned short* VT = vtbuf + (long)bh * 65536;   // [64 d][1024 n]
    unsigned short* O = obuf + (long)bh * 65536;
    int t = threadIdx.x, lane = t & 63, w = t >> 6;
    int lrow = lane >> 4, lcol = lane & 15;
    const float NEG = -__builtin_inff();

    #pragma unroll
    for (int pass = 0; pass < 2; ++pass) {
        int qt = pass == 0 ? j : 31 - j;
        int qbase = qt * 32;
        int T = qt + 1;                                // number of 32-key tiles

        bf16x8 qf[2][2];
        #pragma unroll
        for (int qg = 0; qg < 2; ++qg)
            #pragma unroll
            for (int kc = 0; kc < 2; ++kc)
                qf[qg][kc] = ld_frag(Q + (long)(qbase + qg * 16 + lcol) * 64 + kc * 32 + lrow * 8);

        f32x4 acc[2][4] = {};
        float m_i[2] = {NEG, NEG}, l_i[2] = {0.f, 0.f};

        if (w < T) {
            int kt = w * 32;
            bf16x8 kf[2][2];
            #pragma unroll
            for (int kg = 0; kg < 2; ++kg)
                #pragma unroll
                for (int kc = 0; kc < 2; ++kc)
                    kf[kg][kc] = ld_frag(Kp + (long)(kt + kg * 16 + lcol) * 64 + kc * 32 + lrow * 8);

            for (;; kt += 128) {
                // --- S^T = K * Q ---
                f32x4 s[2][2] = {};
                __builtin_amdgcn_s_setprio(1);
                #pragma unroll
                for (int kg = 0; kg < 2; ++kg)
                    #pragma unroll
                    for (int kc = 0; kc < 2; ++kc) {
                        s[0][kg] = __builtin_amdgcn_mfma_f32_16x16x32_bf16(kf[kg][kc], qf[0][kc], s[0][kg], 0, 0, 0);
                        s[1][kg] = __builtin_amdgcn_mfma_f32_16x16x32_bf16(kf[kg][kc], qf[1][kc], s[1][kg], 0, 0, 0);
                    }
                __builtin_amdgcn_s_setprio(0);

                bool more = kt + 128 < T * 32;
                bf16x8 kn[2][2];
                if (more) {
                    #pragma unroll
                    for (int kg = 0; kg < 2; ++kg)
                        #pragma unroll
                        for (int kc = 0; kc < 2; ++kc)
                            kn[kg][kc] = ld_frag(Kp + (long)(kt + 128 + kg * 16 + lcol) * 64 + kc * 32 + lrow * 8);
                }
                bf16x8 vf[4];
                #pragma unroll
                for (int dg = 0; dg < 4; ++dg)
                    vf[dg] = ld_frag(VT + (long)(dg * 16 + lcol) * 1024 + kt + lrow * 8);

                // --- lane-local online softmax with defer-max (THR=8) ---
                float tv[2][8], pmax[2];
                #pragma unroll
                for (int qg = 0; qg < 2; ++qg) {
                    int q = qbase + qg * 16 + lcol;
                    float mx = NEG;
                    #pragma unroll
                    for (int kg = 0; kg < 2; ++kg)
                        #pragma unroll
                        for (int r = 0; r < 4; ++r) {
                            int kglob = kt + kg * 16 + lrow * 4 + r;
                            float v = s[qg][kg][r] * 0.125f;
                            tv[qg][kg * 4 + r] = kglob > q ? NEG : v;
                            mx = fmaxf(mx, tv[qg][kg * 4 + r]);
                        }
                    mx = fmaxf(mx, __shfl_xor(mx, 16));
                    mx = fmaxf(mx, __shfl_xor(mx, 32));
                    pmax[qg] = mx;
                }
                float alpha[2] = {1.f, 1.f};
                bool small = (pmax[0] - m_i[0] <= 8.f) && (pmax[1] - m_i[1] <= 8.f);
                if (!__all(small)) {
                    #pragma unroll
                    for (int qg = 0; qg < 2; ++qg) {
                        float mnew = fmaxf(m_i[qg], pmax[qg]);
                        alpha[qg] = __expf(m_i[qg] - mnew);
                        m_i[qg] = mnew;
                    }
                    #pragma unroll
                    for (int qg = 0; qg < 2; ++qg)
                        #pragma unroll
                        for (int dg = 0; dg < 4; ++dg)
                            #pragma unroll
                            for (int r = 0; r < 4; ++r)
                                acc[qg][dg][r] *= alpha[qg];
                }
                #pragma unroll
                for (int qg = 0; qg < 2; ++qg) {
                    float p[8], ps = 0.f;
                    #pragma unroll
                    for (int jj = 0; jj < 8; ++jj) { p[jj] = __expf(tv[qg][jj] - m_i[qg]); ps += p[jj]; }
                    #pragma unroll
                    for (int kg = 0; kg < 2; ++kg) {
                        ushort4 pk;
                        pk.x = f2bf(p[kg * 4 + 0]); pk.y = f2bf(p[kg * 4 + 1]);
                        pk.z = f2bf(p[kg * 4 + 2]); pk.w = f2bf(p[kg * 4 + 3]);
                        *(ushort4*)&Ps[w][qg * 16 + lcol][kg * 16 + lrow * 4] = pk;
                    }
                    ps += __shfl_xor(ps, 16);
                    ps += __shfl_xor(ps, 32);
                    l_i[qg] = l_i[qg] * alpha[qg] + ps;
                }

                // --- O^T += V^T * P ---
                bf16x8 pb[2];
                pb[0] = ld_frag(&Ps[w][lcol][lrow * 8]);
                pb[1] = ld_frag(&Ps[w][16 + lcol][lrow * 8]);
                __builtin_amdgcn_s_setprio(1);
                #pragma unroll
                for (int dg = 0; dg < 4; ++dg) {
                    acc[0][dg] = __builtin_amdgcn_mfma_f32_16x16x32_bf16(vf[dg], pb[0], acc[0][dg], 0, 0, 0);
                    acc[1][dg] = __builtin_amdgcn_mfma_f32_16x16x32_bf16(vf[dg], pb[1], acc[1][dg], 0, 0, 0);
                }
                __builtin_amdgcn_s_setprio(0);

                if (!more) break;
                #pragma unroll
                for (int kg = 0; kg < 2; ++kg)
                    #pragma unroll
                    for (int kc = 0; kc < 2; ++kc)
                        kf[kg][kc] = kn[kg][kc];
            }
        }

        // --- merge 4 wave-partials through LDS ---
        __syncthreads();
        #pragma unroll
        for (int qg = 0; qg < 2; ++qg) {
            int q = qg * 16 + lcol;
            if (lrow == 0) { mS[w * 32 + q] = m_i[qg]; lS[w * 32 + q] = l_i[qg]; }
            #pragma unroll
            for (int dg = 0; dg < 4; ++dg)
                *(f32x4*)&accS[(w * 32 + q) * 68 + dg * 16 + lrow * 4] = acc[qg][dg];
        }
        __syncthreads();

        {
            int qq = t >> 3, d0 = (t & 7) * 8;
            float m0 = mS[qq], m1 = mS[32 + qq], m2 = mS[64 + qq], m3 = mS[96 + qq];
            float M = fmaxf(fmaxf(m0, m1), fmaxf(m2, m3));
            float e0 = __expf(m0 - M), e1 = __expf(m1 - M), e2 = __expf(m2 - M), e3 = __expf(m3 - M);
            float L = e0 * lS[qq] + e1 * lS[32 + qq] + e2 * lS[64 + qq] + e3 * lS[96 + qq];
            float inv = 1.f / L;
            const float* a0 = &accS[qq * 68 + d0];
            const float* a1 = &accS[(32 + qq) * 68 + d0];
            const float* a2 = &accS[(64 + qq) * 68 + d0];
            const float* a3 = &accS[(96 + qq) * 68 + d0];
            unsigned short h[8];
            #pragma unroll
            for (int jj = 0; jj < 8; ++jj)
                h[jj] = f2bf((e0 * a0[jj] + e1 * a1[jj] + e2 * a2[jj] + e3 * a3[jj]) * inv);
            uint4 pk;
            pk.x = (unsigned)h[0] | ((unsigned)h[1] << 16);
            pk.y = (unsigned)h[2] | ((unsigned)h[3] << 16);
            pk.z = (unsigned)h[4] | ((unsigned)h[5] << 16);
            pk.w = (unsigned)h[6] | ((unsigned)h[7] << 16);
            *(uint4*)&O[(long)(qbase + qq) * 64 + d0] = pk;
        }
        __syncthreads();
    }
}

extern "C" void kernel_launch(void* const* d_in, const int* in_sizes, int n_in,
                              void* d_out, int out_size, void* d_ws, size_t ws_size,
                              hipStream_t stream) {
    const float* x    = (const float*)d_in[0];
    const float* Wqkv = (const float*)d_in[1];
    const float* bqkv = (const float*)d_in[2];
    const float* Wfc  = (const float*)d_in[3];
    const float* bfc  = (const float*)d_in[4];
    float* out = (float*)d_out;

    unsigned short* ws    = (unsigned short*)d_ws;
    unsigned short* xb    = ws;                    // 4M elems; dead after gemm<0>
    unsigned short* wqkvT = xb + (4u << 20);       // 3M
    unsigned short* wfcT  = wqkvT + (3u << 20);    // 1M
    unsigned short* qb    = wfcT + (1u << 20);     // 4M
    unsigned short* kb    = qb + (4u << 20);       // 4M
    unsigned short* vb    = kb + (4u << 20);       // 4M; dead after transpose_v
    unsigned short* vbT   = xb;                    // reuse xb
    unsigned short* ob    = vb;                    // reuse vb
    // total ws: 40 MB

    cvt_bf16<<<dim3(2048), dim3(256), 0, stream>>>(x, xb, (4 << 20) / 4);
    transpose_cvt<<<dim3(3072 / 32, 1024 / 32), dim3(32, 8), 0, stream>>>(Wqkv, wqkvT, 1024, 3072);
    transpose_cvt<<<dim3(1024 / 32, 1024 / 32), dim3(32, 8), 0, stream>>>(Wfc, wfcT, 1024, 1024);

    gemm128<0><<<dim3(24, 32), dim3(256), 0, stream>>>(xb, wqkvT, bqkv, qb, kb, vb, nullptr);
    transpose_v<<<dim3(32, 2, 64), dim3(32, 8), 0, stream>>>(vb, vbT);
    attn<<<dim3(1024), dim3(256), 0, stream>>>(qb, kb, vbT, ob);
    gemm128<1><<<dim3(8, 32), dim3(256), 0, stream>>>(ob, wfcT, bfc, nullptr, nullptr, nullptr, out);
}